// Round 1
// baseline (750.035 us; speedup 1.0000x reference)
//
#include <hip/hip_runtime.h>
#include <math.h>

#define NB 256
#define NC 512
#define NP 196
#define NIT 32
#define PT 49   // p/q tile (196 = 4*49)

__device__ __forceinline__ float sigf(float z){ return 1.0f/(1.0f+expf(-z)); }

// ---------------- prep: pos_logits, colsum, neg_val, dist_to_zero, sim1, sim2 ----------------
__global__ __launch_bounds__(256) void prep_kernel(
    const float* __restrict__ img, const float* __restrict__ aud,
    float* __restrict__ pl, float* __restrict__ cs, float* __restrict__ d0,
    float* __restrict__ nv, float* __restrict__ sim1, float* __restrict__ sim2,
    float* __restrict__ out_pl)
{
  const int b = blockIdx.x, tid = threadIdx.x;
  const float* imgb = img + (size_t)b*NC*NP;
  __shared__ float s_aud[NC];
  __shared__ float s_wl[NP];
  __shared__ float s_nv[NC];
  __shared__ double s_redd[256];
  for (int c=tid;c<NC;c+=256) s_aud[c]=aud[b*NC+c];
  __syncthreads();
  float plv=0.f, pmw=0.f, negw=0.f;
  if (tid<NP){
    double a=0.0, s=0.0;
    for (int c=0;c<NC;++c){ float x=imgb[(size_t)c*NP+tid]; a += (double)x*(double)s_aud[c]; s += (double)x; }
    plv=(float)a;
    float csv=(float)s;
    pl[b*NP+tid]=plv; cs[b*NP+tid]=csv; out_pl[b*NP+tid]=plv;
    pmw  = sigf((plv-0.65f)/0.03f);
    negw = 1.0f - sigf((plv-0.40f)/0.03f);
    s_wl[tid]=plv*negw;
  }
  // block reductions for sim1 (num,den) and sim2 (num,den)
  double r[4];
  r[0]=(tid<NP)?(double)pmw*(double)plv:0.0;
  r[1]=(tid<NP)?(double)pmw:0.0;
  r[2]=(tid<NP)?(double)negw*(double)plv:0.0;
  r[3]=(tid<NP)?(double)negw:0.0;
  double res[4];
  for (int i=0;i<4;++i){
    __syncthreads();
    s_redd[tid]=r[i];
    __syncthreads();
    for (int s=128;s>0;s>>=1){ if (tid<s) s_redd[tid]+=s_redd[tid+s]; __syncthreads(); }
    res[i]=s_redd[0];
  }
  if (tid==0){
    sim1[b]=(float)(res[0]/res[1]);
    sim2[b]=(float)(res[2]/res[3]);
  }
  __syncthreads();
  // neg_val[c] = mean_p img[c,p] * (pl[p]*negw[p])
  for (int c=tid;c<NC;c+=256){
    const float* row = imgb + (size_t)c*NP;
    double a=0.0;
    for (int p=0;p<NP;++p) a += (double)row[p]*(double)s_wl[p];
    float v=(float)(a/(double)NP);
    nv[b*NC+c]=v; s_nv[c]=v;
  }
  __syncthreads();
  // dist_to_zero
  if (tid<NP){
    double a=0.0;
    const double e=(double)1e-6f;
    for (int c=0;c<NC;++c){
      double t=(double)imgb[(size_t)c*NP+tid]*(double)plv - (double)s_nv[c] + e;
      a += t*t;
    }
    d0[b*NP+tid]=(float)sqrt(a);
  }
}

// ---------------- Gram of img columns: G[b][p][q] = sum_c img[c,p]*img[c,q] ----------------
__global__ __launch_bounds__(256) void gram_kernel(const float* __restrict__ img, float* __restrict__ G)
{
  const int b = blockIdx.x, q0 = blockIdx.y*PT, tid = threadIdx.x;
  const float* imgb = img + (size_t)b*NC*NP;
  float acc[PT];
  #pragma unroll
  for (int j=0;j<PT;++j) acc[j]=0.f;
  for (int c=0;c<NC;++c){
    const float* row = imgb + (size_t)c*NP;
    float x = (tid<NP)? row[tid] : 0.f;
    #pragma unroll
    for (int j=0;j<PT;++j) acc[j] = fmaf(x, row[q0+j], acc[j]);  // row[q0+j] wave-uniform -> s_load
  }
  if (tid<NP){
    float* gp = G + ((size_t)b*NP + tid)*NP + q0;
    #pragma unroll
    for (int j=0;j<PT;++j) gp[j]=acc[j];
  }
}

// ---------------- the 32-iteration selection loop (one block per b) ----------------
__global__ __launch_bounds__(256) void loop_kernel(
    const float* __restrict__ img, const float* __restrict__ pl,
    const float* __restrict__ cs, const float* __restrict__ d0,
    const float* __restrict__ G, float* __restrict__ obj /* [NIT][NB][NC] */)
{
  const int b = blockIdx.x, tid = threadIdx.x;
  const float* imgb = img + (size_t)b*NC*NP;
  const float* Gb = G + (size_t)b*NP*NP;
  __shared__ float s_pos[256];
  __shared__ float s_pl[NP], s_csL[NP], s_d0[NP], s_gd[NP];
  __shared__ float s_red[256];
  __shared__ int   s_redi[256];
  __shared__ int   s_end;
  bool already=false;
  if (tid<NP){
    float p_=pl[b*NP+tid];
    s_pl[tid]=p_;
    s_csL[tid]=p_*cs[b*NP+tid];
    s_d0[tid]=d0[b*NP+tid];
    s_gd[tid]=Gb[(size_t)tid*NP+tid];
    s_pos[tid]=p_;
  } else s_pos[tid]=-INFINITY;
  if (tid==0) s_end=0;
  __syncthreads();
  for (int t=0;t<NIT;++t){
    // argmax (first occurrence of max, numpy semantics)
    s_red[tid]=s_pos[tid]; s_redi[tid]=tid;
    __syncthreads();
    for (int s=128;s>0;s>>=1){
      if (tid<s){
        float v1=s_red[tid], v2=s_red[tid+s];
        int i1=s_redi[tid], i2=s_redi[tid+s];
        if (v2>v1 || (v2==v1 && i2<i1)){ s_red[tid]=v2; s_redi[tid]=i2; }
      }
      __syncthreads();
    }
    const int q = s_redi[0];
    const int endp = s_end;
    const float plq = s_pl[q];
    const float gqq = s_gd[q];
    const float csLq = s_csL[q];
    // obj[t][b][:] write (zeros when endpoint already set)
    {
      float* op = obj + ((size_t)t*NB + b)*NC;
      for (int c=tid;c<NC;c+=256){
        float v = endp ? 0.0f : imgb[(size_t)c*NP + q]*plq;
        op[c]=v;
      }
    }
    // distances via Gram expansion (double for sub-reference-noise accuracy)
    int posf=0;
    if (tid<NP){
      float Gpq = Gb[(size_t)q*NP + tid];
      double plp=(double)s_pl[tid], dq=(double)plq;
      const double e=(double)1e-6f;
      double d2 = plp*plp*(double)s_gd[tid]
                - 2.0*plp*dq*(double)Gpq
                + dq*dq*(double)gqq
                + 2.0*e*((double)s_csL[tid]-(double)csLq)
                + (double)NC*e*e;
      if (d2<0.0) d2=0.0;
      double dl = sqrt(d2);
      if (dl < (double)s_d0[tid] && !already) posf=1;
    }
    __syncthreads();            // done reading s_redi[0]
    s_redi[tid]=posf;
    __syncthreads();
    for (int s=128;s>0;s>>=1){ if (tid<s) s_redi[tid]+=s_redi[tid+s]; __syncthreads(); }
    const int cnt = s_redi[0];
    if (posf) already=true;
    if (tid<NP) s_pos[tid] = s_pos[tid]*(posf?0.0f:1.0f);
    __syncthreads();
    s_red[tid]=(tid<NP)?s_pos[tid]:-INFINITY;
    __syncthreads();
    for (int s=128;s>0;s>>=1){ if (tid<s) s_red[tid]=fmaxf(s_red[tid],s_red[tid+s]); __syncthreads(); }
    if (tid==0){
      if (cnt==0 || s_red[0]<0.1f) s_end=1;
    }
    __syncthreads();
  }
}

// ---------------- aud transpose (audT[c][k] = aud[k][c]) ----------------
__global__ __launch_bounds__(256) void transpose_aud(const float* __restrict__ aud, float* __restrict__ audT)
{
  int i = blockIdx.x*256+threadIdx.x;          // 512*256 = 131072
  int c = i>>8, k = i&255;
  audT[i] = aud[(size_t)k*NC + c];
}

// ---------------- fused all_logits GEMM + sigmoid-weighted partial sums ----------------
__global__ __launch_bounds__(256) void simgemm_kernel(
    const float* __restrict__ img, const float* __restrict__ audT,
    float* __restrict__ pWA, float* __restrict__ pW)
{
  const int b = blockIdx.x, pt = blockIdx.y, p0 = pt*PT;
  const int k = threadIdx.x;
  const float* imgb = img + (size_t)b*NC*NP + p0;
  float acc[PT];
  #pragma unroll
  for (int j=0;j<PT;++j) acc[j]=0.f;
  for (int c=0;c<NC;++c){
    float av = audT[(size_t)c*NB + k];                 // coalesced
    const float* row = imgb + (size_t)c*NP;            // wave-uniform -> s_load
    #pragma unroll
    for (int j=0;j<PT;++j) acc[j] = fmaf(av, row[j], acc[j]);
  }
  double swa=0.0, sw=0.0;
  #pragma unroll
  for (int j=0;j<PT;++j){
    float v=acc[j];
    float w=sigf((v-0.65f)/0.03f);
    swa += (double)w*(double)v;
    sw  += (double)w;
  }
  pWA[((size_t)pt*NB + b)*NB + k]=(float)swa;
  pW [((size_t)pt*NB + b)*NB + k]=(float)sw;
}

__global__ __launch_bounds__(256) void reduce_sims(
    const float* __restrict__ pWA, const float* __restrict__ pW,
    float* __restrict__ sumWA, float* __restrict__ sumW)
{
  int i = blockIdx.x*256+threadIdx.x;  // 65536
  double a=0.0, w=0.0;
  for (int pt=0;pt<4;++pt){ a+=(double)pWA[(size_t)pt*NB*NB+i]; w+=(double)pW[(size_t)pt*NB*NB+i]; }
  sumWA[i]=(float)a; sumW[i]=(float)w;
}

// ---------------- loss ----------------
__global__ __launch_bounds__(256) void finalize_kernel(
    const float* __restrict__ sim1, const float* __restrict__ sim2,
    const float* __restrict__ sumWA, const float* __restrict__ sumW,
    float* __restrict__ out_loss)
{
  const int b = threadIdx.x;
  const float T = 0.07f;
  float l0 = sim1[b]/T;
  float ll = sim2[b]/T;
  float m = fmaxf(l0,ll);
  for (int k=0;k<NB;++k){
    float s = sumWA[(size_t)b*NB+k]/sumW[(size_t)b*NB+k];
    if (k==b) s *= -99.0f;
    m = fmaxf(m, s/T);
  }
  double se = exp((double)(l0-m)) + exp((double)(ll-m));
  for (int k=0;k<NB;++k){
    float s = sumWA[(size_t)b*NB+k]/sumW[(size_t)b*NB+k];
    if (k==b) s *= -99.0f;
    se += exp((double)(s/T-m));
  }
  float lsm0 = (float)((double)(l0-m) - log(se));
  __shared__ double s_redd[256];
  s_redd[b] = -(double)lsm0;
  __syncthreads();
  for (int s=128;s>0;s>>=1){ if (b<s) s_redd[b]+=s_redd[b+s]; __syncthreads(); }
  if (b==0) out_loss[0]=(float)(s_redd[0]/(double)NB);
}

extern "C" void kernel_launch(void* const* d_in, const int* in_sizes, int n_in,
                              void* d_out, int out_size, void* d_ws, size_t ws_size,
                              hipStream_t stream)
{
  const float* img = (const float*)d_in[0];
  const float* aud = (const float*)d_in[1];
  float* out = (float*)d_out;
  float* ws  = (float*)d_ws;

  // ws layout (floats)
  float* pl    = ws;                       // 50176
  float* cs    = pl    + NB*NP;            // 50176
  float* d0    = cs    + NB*NP;            // 50176
  float* nv    = d0    + NB*NP;            // 131072
  float* sim1  = nv    + NB*NC;            // 256
  float* sim2  = sim1  + NB;               // 256
  float* sumWA = sim2  + NB;               // 65536
  float* sumW  = sumWA + NB*NB;            // 65536
  float* pWA   = sumW  + NB*NB;            // 262144
  float* pW    = pWA   + 4*NB*NB;          // 262144
  float* audT  = pW    + 4*NB*NB;          // 131072
  float* G     = audT  + NC*NB;            // 9834496  (~39.3 MB)

  float* out_loss = out;
  float* out_pl   = out + 1;
  float* out_obj  = out + 1 + NB*NP;

  hipLaunchKernelGGL(transpose_aud, dim3(NC*NB/256), dim3(256), 0, stream, aud, audT);
  hipLaunchKernelGGL(prep_kernel,   dim3(NB),        dim3(256), 0, stream, img, aud, pl, cs, d0, nv, sim1, sim2, out_pl);
  hipLaunchKernelGGL(gram_kernel,   dim3(NB,4),      dim3(256), 0, stream, img, G);
  hipLaunchKernelGGL(simgemm_kernel,dim3(NB,4),      dim3(256), 0, stream, img, audT, pWA, pW);
  hipLaunchKernelGGL(reduce_sims,   dim3(NB*NB/256), dim3(256), 0, stream, pWA, pW, sumWA, sumW);
  hipLaunchKernelGGL(loop_kernel,   dim3(NB),        dim3(256), 0, stream, img, pl, cs, d0, G, out_obj);
  hipLaunchKernelGGL(finalize_kernel,dim3(1),        dim3(256), 0, stream, sim1, sim2, sumWA, sumW, out_loss);
}

// Round 2
// 470.403 us; speedup vs baseline: 1.5945x; 1.5945x over previous
//
#include <hip/hip_runtime.h>
#include <math.h>

#define NB 256
#define NC 512
#define NP 196
#define NIT 32
#define PROWS 208    // 13 tiles of 16
#define PSTRIDE 36   // shorts per panel row (72B: b64-aligned, 16-distinct-bank reads)

typedef __attribute__((ext_vector_type(8))) short bf16x8;
typedef __attribute__((ext_vector_type(4))) short bf16x4;
typedef __attribute__((ext_vector_type(4))) float f32x4;

__device__ __forceinline__ float sigf(float z){ return 1.0f/(1.0f+expf(-z)); }

__device__ __forceinline__ unsigned short f2bf(float x){
  union{float f; unsigned u;} v; v.f=x;
  unsigned r = v.u + 0x7FFFu + ((v.u>>16)&1u);
  return (unsigned short)(r>>16);
}
__device__ __forceinline__ float bf2f(unsigned short h){
  union{float f; unsigned u;} v; v.u = ((unsigned)h)<<16; return v.f;
}

__device__ __forceinline__ bf16x8 read_frag(const short* sm, int tile, int lane){
  int r = tile*16 + (lane & 15);
  int o = lane >> 4;
  const short* p = sm + r*PSTRIDE + o*8;
  bf16x4 a = *(const bf16x4*)p;
  bf16x4 b = *(const bf16x4*)(p+4);
  return __builtin_shufflevector(a, b, 0,1,2,3,4,5,6,7);
}

// ---------------- aud -> bf16 ----------------
__global__ __launch_bounds__(256) void aud2bf_kernel(const float* __restrict__ aud, unsigned short* __restrict__ aud_bf)
{
  int i = blockIdx.x*256 + threadIdx.x;   // 131072
  aud_bf[i] = f2bf(aud[i]);
}

// ---------------- prep: pos_logits, colsum, dist_to_zero, neg_val, sim1, sim2 ----------------
__global__ __launch_bounds__(256) void prep_kernel(
    const float* __restrict__ img, const float* __restrict__ aud,
    float* __restrict__ pl, float* __restrict__ cs, float* __restrict__ d0,
    float* __restrict__ sim1, float* __restrict__ sim2,
    float* __restrict__ out_pl)
{
  const int b = blockIdx.x, tid = threadIdx.x;
  const float* imgb = img + (size_t)b*NC*NP;
  __shared__ float s_aud[NC];
  __shared__ float s_wl[NP];
  __shared__ float s_nv[NC];
  __shared__ double s_redd[256];
  for (int c=tid;c<NC;c+=256) s_aud[c]=aud[b*NC+c];
  __syncthreads();
  float plv=0.f, pmw=0.f, negw=0.f;
  if (tid<NP){
    double a=0.0, s=0.0;
    for (int c=0;c<NC;++c){ float x=imgb[(size_t)c*NP+tid]; a += (double)x*(double)s_aud[c]; s += (double)x; }
    plv=(float)a;
    float csv=(float)s;
    pl[b*NP+tid]=plv; cs[b*NP+tid]=csv; out_pl[b*NP+tid]=plv;
    pmw  = sigf((plv-0.65f)/0.03f);
    negw = 1.0f - sigf((plv-0.40f)/0.03f);
    s_wl[tid]=plv*negw;
  }
  double r[4];
  r[0]=(tid<NP)?(double)pmw*(double)plv:0.0;
  r[1]=(tid<NP)?(double)pmw:0.0;
  r[2]=(tid<NP)?(double)negw*(double)plv:0.0;
  r[3]=(tid<NP)?(double)negw:0.0;
  double res[4];
  for (int i=0;i<4;++i){
    __syncthreads();
    s_redd[tid]=r[i];
    __syncthreads();
    for (int s=128;s>0;s>>=1){ if (tid<s) s_redd[tid]+=s_redd[tid+s]; __syncthreads(); }
    res[i]=s_redd[0];
  }
  if (tid==0){
    sim1[b]=(float)(res[0]/res[1]);
    sim2[b]=(float)(res[2]/res[3]);
  }
  __syncthreads();
  for (int c=tid;c<NC;c+=256){
    const float* row = imgb + (size_t)c*NP;
    double a=0.0;
    for (int p=0;p<NP;++p) a += (double)row[p]*(double)s_wl[p];
    s_nv[c]=(float)(a/(double)NP);
  }
  __syncthreads();
  if (tid<NP){
    double a=0.0;
    const double e=(double)1e-6f;
    for (int c=0;c<NC;++c){
      double t=(double)imgb[(size_t)c*NP+tid]*(double)plv - (double)s_nv[c] + e;
      a += t*t;
    }
    d0[b*NP+tid]=(float)sqrt(a);
  }
}

// ---------------- Gram via split-bf16 MFMA: G = hi*hi + hi*lo + lo*hi ----------------
__global__ __launch_bounds__(256) void gram_mfma(const float* __restrict__ img, float* __restrict__ G)
{
  const int bid = blockIdx.x;
  const int L = (bid & 7)*128 + (bid >> 3);        // XCD-grouping: 4 blocks of same b on one XCD
  const int b = L >> 2, g = L & 3;
  const int tp0 = (g==0)?0:(3*g+1), ntp = (g==0)?4:3;
  const int tid = threadIdx.x, lane = tid & 63, w = tid >> 6;
  const int tq0 = (w==0)?0:(3*w+1), ntq = (w==0)?4:3;
  const float* imgb = img + (size_t)b*NC*NP;
  float* Gb = G + (size_t)b*NP*NP;
  __shared__ short smh[PROWS*PSTRIDE];
  __shared__ short sml[PROWS*PSTRIDE];

  f32x4 acc[4][4];
  #pragma unroll
  for (int i=0;i<4;++i)
    #pragma unroll
    for (int j=0;j<4;++j) acc[i][j] = (f32x4){0.f,0.f,0.f,0.f};

  for (int ks=0; ks<16; ++ks){
    const int c0 = ks*32;
    __syncthreads();
    for (int i=tid; i<PROWS*8; i+=256){
      int p = i % PROWS, cq = i / PROWS;
      float x[4] = {0.f,0.f,0.f,0.f};
      if (p < NP){
        const float* bp = imgb + (size_t)(c0+cq*4)*NP + p;
        x[0]=bp[0]; x[1]=bp[NP]; x[2]=bp[2*NP]; x[3]=bp[3*NP];
      }
      unsigned hh[4], ll[4];
      #pragma unroll
      for (int cc=0;cc<4;++cc){
        unsigned short h = f2bf(x[cc]);
        float rr = x[cc] - bf2f(h);
        hh[cc]=h; ll[cc]=f2bf(rr);
      }
      uint2 hv, lv;
      hv.x = hh[0]|(hh[1]<<16); hv.y = hh[2]|(hh[3]<<16);
      lv.x = ll[0]|(ll[1]<<16); lv.y = ll[2]|(ll[3]<<16);
      *(uint2*)&smh[p*PSTRIDE + cq*4] = hv;
      *(uint2*)&sml[p*PSTRIDE + cq*4] = lv;
    }
    __syncthreads();

    bf16x8 Ah[4], Al[4], Bh[4], Bl[4];
    #pragma unroll
    for (int i=0;i<4;++i){
      if (i<ntp){ Ah[i]=read_frag(smh, tp0+i, lane); Al[i]=read_frag(sml, tp0+i, lane); }
      if (i<ntq){ Bh[i]=read_frag(smh, tq0+i, lane); Bl[i]=read_frag(sml, tq0+i, lane); }
    }
    #pragma unroll
    for (int i=0;i<4;++i){
      #pragma unroll
      for (int j=0;j<4;++j){
        if (i<ntp && j<ntq){
          acc[i][j] = __builtin_amdgcn_mfma_f32_16x16x32_bf16(Ah[i], Bh[j], acc[i][j], 0,0,0);
          acc[i][j] = __builtin_amdgcn_mfma_f32_16x16x32_bf16(Ah[i], Bl[j], acc[i][j], 0,0,0);
          acc[i][j] = __builtin_amdgcn_mfma_f32_16x16x32_bf16(Al[i], Bh[j], acc[i][j], 0,0,0);
        }
      }
    }
  }

  const int r0 = (lane>>4)*4, colL = lane & 15;
  #pragma unroll
  for (int i=0;i<4;++i){
    #pragma unroll
    for (int j=0;j<4;++j){
      if (i<ntp && j<ntq){
        int row = (tp0+i)*16 + r0;
        int col = (tq0+j)*16 + colL;
        if (col < NP){
          #pragma unroll
          for (int jj=0;jj<4;++jj){
            if (row+jj < NP) Gb[(size_t)(row+jj)*NP + col] = acc[i][j][jj];
          }
        }
      }
    }
  }
}

// ---------------- all_logits GEMM (bf16 MFMA) fused with sigmoid-weighted sums ----------------
__global__ __launch_bounds__(256) void simgemm_mfma(
    const float* __restrict__ img, const unsigned short* __restrict__ aud_bf,
    float* __restrict__ sumWA, float* __restrict__ sumW)
{
  const int bid = blockIdx.x;
  const int L = (bid & 7)*128 + (bid >> 3);
  const int b = L >> 2, ng = L & 3;                 // ng: 4 n-tiles (64 audio cols)
  const int tid = threadIdx.x, lane = tid & 63, w = tid >> 6;
  const int tp0 = (w==0)?0:(3*w+1), ntp = (w==0)?4:3;   // waves split the 13 p-tiles
  const float* imgb = img + (size_t)b*NC*NP;
  __shared__ short smh[PROWS*PSTRIDE];
  __shared__ float sred[2][4][16][16];   // [wa/w][ntile][wave*4+lanegrp][col]

  f32x4 acc[4][4];
  #pragma unroll
  for (int i=0;i<4;++i)
    #pragma unroll
    for (int j=0;j<4;++j) acc[i][j] = (f32x4){0.f,0.f,0.f,0.f};

  for (int ks=0; ks<16; ++ks){
    const int c0 = ks*32;
    __syncthreads();
    for (int i=tid; i<PROWS*8; i+=256){
      int p = i % PROWS, cq = i / PROWS;
      float x[4] = {0.f,0.f,0.f,0.f};
      if (p < NP){
        const float* bp = imgb + (size_t)(c0+cq*4)*NP + p;
        x[0]=bp[0]; x[1]=bp[NP]; x[2]=bp[2*NP]; x[3]=bp[3*NP];
      }
      uint2 hv;
      hv.x = (unsigned)f2bf(x[0]) | ((unsigned)f2bf(x[1])<<16);
      hv.y = (unsigned)f2bf(x[2]) | ((unsigned)f2bf(x[3])<<16);
      *(uint2*)&smh[p*PSTRIDE + cq*4] = hv;
    }
    __syncthreads();

    bf16x8 Ah[4], Bn[4];
    #pragma unroll
    for (int i=0;i<4;++i){
      if (i<ntp) Ah[i]=read_frag(smh, tp0+i, lane);
      int k = ng*64 + i*16 + (lane & 15);
      int c = c0 + (lane>>4)*8;
      Bn[i] = *(const bf16x8*)(aud_bf + (size_t)k*NC + c);
    }
    #pragma unroll
    for (int i=0;i<4;++i){
      #pragma unroll
      for (int n=0;n<4;++n){
        if (i<ntp)
          acc[i][n] = __builtin_amdgcn_mfma_f32_16x16x32_bf16(Ah[i], Bn[n], acc[i][n], 0,0,0);
      }
    }
  }

  // sigmoid-weighted reduce over rows (pixels), masking pad rows >=196
  const int r0 = (lane>>4)*4, colL = lane & 15;
  float swa[4]={0.f,0.f,0.f,0.f}, sw[4]={0.f,0.f,0.f,0.f};
  #pragma unroll
  for (int i=0;i<4;++i){
    #pragma unroll
    for (int n=0;n<4;++n){
      if (i<ntp){
        int rowbase = (tp0+i)*16 + r0;
        #pragma unroll
        for (int jj=0;jj<4;++jj){
          if (rowbase+jj < NP){
            float v = acc[i][n][jj];
            float wgt = sigf((v-0.65f)/0.03f);
            swa[n] += wgt*v; sw[n] += wgt;
          }
        }
      }
    }
  }
  __syncthreads();
  #pragma unroll
  for (int n=0;n<4;++n){
    sred[0][n][w*4 + (lane>>4)][colL] = swa[n];
    sred[1][n][w*4 + (lane>>4)][colL] = sw[n];
  }
  __syncthreads();
  if (tid < 64){
    int n = tid >> 4, col = tid & 15;
    double a=0.0, s=0.0;
    for (int k=0;k<16;++k){ a += (double)sred[0][n][k][col]; s += (double)sred[1][n][k][col]; }
    int kcol = ng*64 + n*16 + col;
    sumWA[(size_t)b*NB + kcol] = (float)a;
    sumW [(size_t)b*NB + kcol] = (float)s;
  }
}

// ---------------- 32-iteration selection loop: 2 barriers/iter ----------------
__global__ __launch_bounds__(256) void loop_kernel(
    const float* __restrict__ img, const float* __restrict__ pl,
    const float* __restrict__ cs, const float* __restrict__ d0,
    const float* __restrict__ G, float* __restrict__ obj /* [NIT][NB][NC] */)
{
  const int b = blockIdx.x, tid = threadIdx.x, lane = tid & 63, w = tid >> 6;
  const float* imgb = img + (size_t)b*NC*NP;
  const float* Gb = G + (size_t)b*NP*NP;
  __shared__ float s_pl[NP], s_csL[NP], s_gd[NP];
  __shared__ float s_cand_v[4]; __shared__ int s_cand_i[4];
  __shared__ int s_cnt[4]; __shared__ float s_mx[4];

  float plv=0.f, d0v=0.f;
  if (tid<NP){
    plv = pl[b*NP+tid];
    s_pl[tid]=plv;
    s_csL[tid]=plv*cs[b*NP+tid];
    s_gd[tid]=Gb[(size_t)tid*NP+tid];
    d0v = d0[b*NP+tid];
  }
  float posv = (tid<NP)? plv : -INFINITY;
  bool already=false, endp=false;
  __syncthreads();

  for (int t=0;t<NIT;++t){
    // per-wave argmax candidate (first-occurrence tie-break)
    float v = posv; int ix = tid;
    #pragma unroll
    for (int m=1;m<64;m<<=1){
      float vv = __shfl_xor(v, m);
      int   ii = __shfl_xor(ix, m);
      if (vv>v || (vv==v && ii<ix)){ v=vv; ix=ii; }
    }
    if (lane==0){ s_cand_v[w]=v; s_cand_i[w]=ix; }
    __syncthreads();
    float bv = s_cand_v[0]; int q = s_cand_i[0];
    #pragma unroll
    for (int w2=1;w2<4;++w2){
      float cv=s_cand_v[w2]; int ci=s_cand_i[w2];
      if (cv>bv || (cv==bv && ci<q)){ bv=cv; q=ci; }
    }
    const float plq = s_pl[q], gqq = s_gd[q], csLq = s_csL[q];

    // obj[t][b][:]
    {
      float* op = obj + ((size_t)t*NB + b)*NC;
      for (int c=tid;c<NC;c+=256) op[c] = endp ? 0.0f : imgb[(size_t)c*NP + q]*plq;
    }

    // pos detect via Gram expansion (double)
    int posf=0;
    if (tid<NP && !already){
      float Gpq = Gb[(size_t)q*NP + tid];
      double plp=(double)posv; // careful: posv may be zeroed; use s_pl value
      plp = (double)s_pl[tid];
      double dq=(double)plq;
      const double e=(double)1e-6f;
      double d2 = plp*plp*(double)s_gd[tid]
                - 2.0*plp*dq*(double)Gpq
                + dq*dq*(double)gqq
                + 2.0*e*((double)s_csL[tid]-(double)csLq)
                + (double)NC*e*e;
      if (d2<0.0) d2=0.0;
      if (sqrt(d2) < (double)d0v) posf=1;
    }
    if (posf){ already=true; posv = posv*0.0f; }

    int cnt = posf; float mx = posv;
    #pragma unroll
    for (int m=1;m<64;m<<=1){
      cnt += __shfl_xor(cnt, m);
      mx = fmaxf(mx, __shfl_xor(mx, m));
    }
    if (lane==0){ s_cnt[w]=cnt; s_mx[w]=mx; }
    __syncthreads();
    int ct = s_cnt[0]+s_cnt[1]+s_cnt[2]+s_cnt[3];
    float mxx = fmaxf(fmaxf(s_mx[0],s_mx[1]),fmaxf(s_mx[2],s_mx[3]));
    if (ct==0 || mxx<0.1f) endp=true;
  }
}

// ---------------- loss ----------------
__global__ __launch_bounds__(256) void finalize_kernel(
    const float* __restrict__ sim1, const float* __restrict__ sim2,
    const float* __restrict__ sumWA, const float* __restrict__ sumW,
    float* __restrict__ out_loss)
{
  const int b = threadIdx.x;
  const float T = 0.07f;
  float l0 = sim1[b]/T;
  float ll = sim2[b]/T;
  float m = fmaxf(l0,ll);
  for (int k=0;k<NB;++k){
    float s = sumWA[(size_t)b*NB+k]/sumW[(size_t)b*NB+k];
    if (k==b) s *= -99.0f;
    m = fmaxf(m, s/T);
  }
  double se = exp((double)(l0-m)) + exp((double)(ll-m));
  for (int k=0;k<NB;++k){
    float s = sumWA[(size_t)b*NB+k]/sumW[(size_t)b*NB+k];
    if (k==b) s *= -99.0f;
    se += exp((double)(s/T-m));
  }
  float lsm0 = (float)((double)(l0-m) - log(se));
  __shared__ double s_redd[256];
  s_redd[b] = -(double)lsm0;
  __syncthreads();
  for (int s=128;s>0;s>>=1){ if (b<s) s_redd[b]+=s_redd[b+s]; __syncthreads(); }
  if (b==0) out_loss[0]=(float)(s_redd[0]/(double)NB);
}

extern "C" void kernel_launch(void* const* d_in, const int* in_sizes, int n_in,
                              void* d_out, int out_size, void* d_ws, size_t ws_size,
                              hipStream_t stream)
{
  const float* img = (const float*)d_in[0];
  const float* aud = (const float*)d_in[1];
  float* out = (float*)d_out;
  float* ws  = (float*)d_ws;

  // ws layout (floats)
  float* pl    = ws;                        // 50176
  float* cs    = pl    + NB*NP;             // 50176
  float* d0    = cs    + NB*NP;             // 50176
  float* sim1  = d0    + NB*NP;             // 256
  float* sim2  = sim1  + NB;                // 256
  float* sumWA = sim2  + NB;                // 65536
  float* sumW  = sumWA + NB*NB;             // 65536
  unsigned short* aud_bf = (unsigned short*)(sumW + NB*NB);  // 131072 ushort = 65536 float slots
  float* G     = sumW + NB*NB + NB*NC/2*1 + NB*NB;           // careful below
  // recompute G cleanly:
  G = (float*)(aud_bf + NB*NC);             // 9,834,496 floats (~39.3 MB)

  float* out_loss = out;
  float* out_pl   = out + 1;
  float* out_obj  = out + 1 + NB*NP;

  hipLaunchKernelGGL(aud2bf_kernel,  dim3(NB*NC/256), dim3(256), 0, stream, aud, aud_bf);
  hipLaunchKernelGGL(prep_kernel,    dim3(NB),        dim3(256), 0, stream, img, aud, pl, cs, d0, sim1, sim2, out_pl);
  hipLaunchKernelGGL(gram_mfma,      dim3(NB*4),      dim3(256), 0, stream, img, G);
  hipLaunchKernelGGL(simgemm_mfma,   dim3(NB*4),      dim3(256), 0, stream, img, aud_bf, sumWA, sumW);
  hipLaunchKernelGGL(loop_kernel,    dim3(NB),        dim3(256), 0, stream, img, pl, cs, d0, G, out_obj);
  hipLaunchKernelGGL(finalize_kernel,dim3(1),         dim3(256), 0, stream, sim1, sim2, sumWA, sumW, out_loss);
}

// Round 3
// 418.811 us; speedup vs baseline: 1.7909x; 1.1232x over previous
//
#include <hip/hip_runtime.h>
#include <hip/hip_bf16.h>
#include <math.h>

#define NB 256
#define NC 512
#define NP 196
#define NIT 32
#define PROWS 208          // 13 tiles of 16

// gram: K-slice 64, stride 72 shorts (144B, 16B-aligned)
#define GKS 64
#define GSTR 72
// simgemm: K-slice 128, stride 136 shorts (272B, 16B-aligned)
#define SKS 128
#define SSTR 136

typedef __attribute__((ext_vector_type(8))) short bf16x8;
typedef __attribute__((ext_vector_type(4))) float f32x4;

__device__ __forceinline__ float sigf(float z){ return 1.0f/(1.0f+expf(-z)); }

__device__ __forceinline__ unsigned short f2bf(float x){
  return __bfloat16_as_ushort(__float2bfloat16(x));
}
__device__ __forceinline__ float bf2f(unsigned short h){
  union{float f; unsigned u;} v; v.u = ((unsigned)h)<<16; return v.f;
}

__device__ __forceinline__ bf16x8 frag_ld(const short* sm, int stride, int tile, int kk, int lane){
  int r = tile*16 + (lane & 15);
  int o = lane >> 4;
  const short* p = sm + r*stride + kk*32 + o*8;
  return *(const bf16x8*)p;
}

// ---------------- aud -> bf16 ----------------
__global__ __launch_bounds__(256) void aud2bf_kernel(const float* __restrict__ aud, unsigned short* __restrict__ aud_bf)
{
  int i = blockIdx.x*256 + threadIdx.x;   // 131072
  aud_bf[i] = f2bf(aud[i]);
}

// ---------------- prep: pos_logits, colsum, dist_to_zero, neg_val, sim1, sim2 ----------------
__global__ __launch_bounds__(256) void prep_kernel(
    const float* __restrict__ img, const float* __restrict__ aud,
    float* __restrict__ pl, float* __restrict__ cs, float* __restrict__ d0,
    float* __restrict__ sim1, float* __restrict__ sim2,
    float* __restrict__ out_pl)
{
  const int b = blockIdx.x, tid = threadIdx.x;
  const float* imgb = img + (size_t)b*NC*NP;
  __shared__ float s_aud[NC];
  __shared__ float s_wl[NP];
  __shared__ float s_nv[NC];
  __shared__ double s_redd[256];
  for (int c=tid;c<NC;c+=256) s_aud[c]=aud[b*NC+c];
  __syncthreads();
  float plv=0.f, pmw=0.f, negw=0.f;
  if (tid<NP){
    double a=0.0, s=0.0;
    for (int c=0;c<NC;++c){ float x=imgb[(size_t)c*NP+tid]; a += (double)x*(double)s_aud[c]; s += (double)x; }
    plv=(float)a;
    float csv=(float)s;
    pl[b*NP+tid]=plv; cs[b*NP+tid]=csv; out_pl[b*NP+tid]=plv;
    pmw  = sigf((plv-0.65f)/0.03f);
    negw = 1.0f - sigf((plv-0.40f)/0.03f);
    s_wl[tid]=plv*negw;
  }
  double r[4];
  r[0]=(tid<NP)?(double)pmw*(double)plv:0.0;
  r[1]=(tid<NP)?(double)pmw:0.0;
  r[2]=(tid<NP)?(double)negw*(double)plv:0.0;
  r[3]=(tid<NP)?(double)negw:0.0;
  double res[4];
  for (int i=0;i<4;++i){
    __syncthreads();
    s_redd[tid]=r[i];
    __syncthreads();
    for (int s=128;s>0;s>>=1){ if (tid<s) s_redd[tid]+=s_redd[tid+s]; __syncthreads(); }
    res[i]=s_redd[0];
  }
  if (tid==0){
    sim1[b]=(float)(res[0]/res[1]);
    sim2[b]=(float)(res[2]/res[3]);
  }
  __syncthreads();
  for (int c=tid;c<NC;c+=256){
    const float* row = imgb + (size_t)c*NP;
    double a=0.0;
    for (int p=0;p<NP;++p) a += (double)row[p]*(double)s_wl[p];
    s_nv[c]=(float)(a/(double)NP);
  }
  __syncthreads();
  if (tid<NP){
    double a=0.0;
    const double e=(double)1e-6f;
    for (int c=0;c<NC;++c){
      double t=(double)imgb[(size_t)c*NP+tid]*(double)plv - (double)s_nv[c] + e;
      a += t*t;
    }
    d0[b*NP+tid]=(float)sqrt(a);
  }
}

// ---------------- Gram via split-bf16 MFMA, one block per b, 8 waves ----------------
__global__ __launch_bounds__(512) void gram_mfma(const float* __restrict__ img, float* __restrict__ G)
{
  const int b = blockIdx.x;
  const int tid = threadIdx.x, lane = tid & 63, w = tid >> 6;
  const int wr = w >> 1, wc = w & 1;                  // 4 row-groups x 2 col-groups
  const int rbase = (wr==0)?0:(3*wr+1), nr = (wr==0)?4:3;
  const int cbase = 7*wc, ncl = 7-wc;
  const float* imgb = img + (size_t)b*NC*NP;
  float* Gb = G + (size_t)b*NP*NP;
  __shared__ short smh[PROWS*GSTR];
  __shared__ short sml[PROWS*GSTR];

  f32x4 acc[4][7];
  #pragma unroll
  for (int i=0;i<4;++i)
    #pragma unroll
    for (int j=0;j<7;++j) acc[i][j] = (f32x4){0.f,0.f,0.f,0.f};

  for (int sl=0; sl<NC/GKS; ++sl){
    __syncthreads();
    // stage: p fast (coalesced), 8 c's per item, write b128 hi+lo
    #pragma unroll
    for (int it=0; it<4; ++it){
      int j = it*512 + tid;
      int p = j & 255, c8 = j >> 8;        // c8 in 0..7
      if (p < PROWS){
        float x[8];
        #pragma unroll
        for (int cc=0;cc<8;++cc){
          int c = sl*GKS + c8*8 + cc;
          x[cc] = (p<NP) ? imgb[(size_t)c*NP + p] : 0.f;
        }
        unsigned hw[4], lw[4];
        #pragma unroll
        for (int k2=0;k2<4;++k2){
          unsigned short h0=f2bf(x[2*k2]), h1=f2bf(x[2*k2+1]);
          float l0 = x[2*k2]-bf2f(h0), l1 = x[2*k2+1]-bf2f(h1);
          hw[k2] = (unsigned)h0 | ((unsigned)h1<<16);
          lw[k2] = (unsigned)f2bf(l0) | ((unsigned)f2bf(l1)<<16);
        }
        *(uint4*)&smh[p*GSTR + c8*8] = *(uint4*)hw;
        *(uint4*)&sml[p*GSTR + c8*8] = *(uint4*)lw;
      }
    }
    __syncthreads();
    #pragma unroll
    for (int kk=0; kk<GKS/32; ++kk){
      bf16x8 Ah[4], Al[4];
      #pragma unroll
      for (int i=0;i<4;++i){
        if (i<nr){ Ah[i]=frag_ld(smh,GSTR,rbase+i,kk,lane); Al[i]=frag_ld(sml,GSTR,rbase+i,kk,lane); }
      }
      #pragma unroll
      for (int j=0;j<7;++j){
        if (j<ncl){
          bf16x8 Bh = frag_ld(smh,GSTR,cbase+j,kk,lane);
          bf16x8 Bl = frag_ld(sml,GSTR,cbase+j,kk,lane);
          #pragma unroll
          for (int i=0;i<4;++i){
            if (i<nr){
              acc[i][j] = __builtin_amdgcn_mfma_f32_16x16x32_bf16(Ah[i], Bh, acc[i][j], 0,0,0);
              acc[i][j] = __builtin_amdgcn_mfma_f32_16x16x32_bf16(Ah[i], Bl, acc[i][j], 0,0,0);
              acc[i][j] = __builtin_amdgcn_mfma_f32_16x16x32_bf16(Al[i], Bh, acc[i][j], 0,0,0);
            }
          }
        }
      }
    }
  }

  const int r0 = (lane>>4)*4, colL = lane & 15;
  #pragma unroll
  for (int i=0;i<4;++i){
    #pragma unroll
    for (int j=0;j<7;++j){
      if (i<nr && j<ncl){
        int row = (rbase+i)*16 + r0;
        int col = (cbase+j)*16 + colL;
        if (col < NP){
          #pragma unroll
          for (int jj=0;jj<4;++jj){
            if (row+jj < NP) Gb[(size_t)(row+jj)*NP + col] = acc[i][j][jj];
          }
        }
      }
    }
  }
}

// ---------------- all_logits GEMM + fused sigmoid sums, one block per b, 8 waves ----------------
__global__ __launch_bounds__(512) void simgemm_mfma(
    const float* __restrict__ img, const unsigned short* __restrict__ aud_bf,
    float* __restrict__ sumWA, float* __restrict__ sumW)
{
  const int b = blockIdx.x;
  const int tid = threadIdx.x, lane = tid & 63, w = tid >> 6;
  const int wr = w >> 2, wc = w & 3;                 // 2 p-groups x 4 n-groups
  const int pbase = (wr==0)?0:7, np = 7-wr;          // 7 / 6 p-tiles
  const float* imgb = img + (size_t)b*NC*NP;
  __shared__ short smh[PROWS*SSTR];
  __shared__ float sred[2][2][4][4][16];

  f32x4 acc[7][4];
  #pragma unroll
  for (int i=0;i<7;++i)
    #pragma unroll
    for (int n=0;n<4;++n) acc[i][n] = (f32x4){0.f,0.f,0.f,0.f};

  for (int sl=0; sl<NC/SKS; ++sl){
    __syncthreads();
    #pragma unroll
    for (int it=0; it<8; ++it){
      int j = it*512 + tid;
      int p = j & 255, c8 = j >> 8;       // c8 in 0..15
      if (p < PROWS){
        float x[8];
        #pragma unroll
        for (int cc=0;cc<8;++cc){
          int c = sl*SKS + c8*8 + cc;
          x[cc] = (p<NP) ? imgb[(size_t)c*NP + p] : 0.f;
        }
        unsigned hw[4];
        #pragma unroll
        for (int k2=0;k2<4;++k2)
          hw[k2] = (unsigned)f2bf(x[2*k2]) | ((unsigned)f2bf(x[2*k2+1])<<16);
        *(uint4*)&smh[p*SSTR + c8*8] = *(uint4*)hw;
      }
    }
    __syncthreads();
    #pragma unroll
    for (int kk=0; kk<SKS/32; ++kk){
      bf16x8 Ah[7];
      #pragma unroll
      for (int i=0;i<7;++i)
        if (i<np) Ah[i]=frag_ld(smh,SSTR,pbase+i,kk,lane);
      #pragma unroll
      for (int n=0;n<4;++n){
        int ntile = wc*4 + n;
        int k = ntile*16 + (lane&15);
        int c = sl*SKS + kk*32 + (lane>>4)*8;
        bf16x8 Bn = *(const bf16x8*)(aud_bf + (size_t)k*NC + c);
        #pragma unroll
        for (int i=0;i<7;++i)
          if (i<np)
            acc[i][n] = __builtin_amdgcn_mfma_f32_16x16x32_bf16(Ah[i], Bn, acc[i][n], 0,0,0);
      }
    }
  }

  // sigmoid-weighted reduce over pixel rows
  float swa[4]={0,0,0,0}, sw[4]={0,0,0,0};
  #pragma unroll
  for (int n=0;n<4;++n){
    #pragma unroll
    for (int i=0;i<7;++i){
      if (i<np){
        int rowbase = (pbase+i)*16 + (lane>>4)*4;
        #pragma unroll
        for (int jj=0;jj<4;++jj){
          if (rowbase+jj < NP){
            float v = acc[i][n][jj];
            float wgt = sigf((v-0.65f)/0.03f);
            swa[n] += wgt*v; sw[n] += wgt;
          }
        }
      }
    }
  }
  // reduce across the 4 row-groups (lanes with same lane&15)
  #pragma unroll
  for (int n=0;n<4;++n){
    swa[n] += __shfl_xor(swa[n],16); swa[n] += __shfl_xor(swa[n],32);
    sw[n]  += __shfl_xor(sw[n],16);  sw[n]  += __shfl_xor(sw[n],32);
  }
  if ((lane&63) < 16){
    #pragma unroll
    for (int n=0;n<4;++n){
      sred[0][wr][wc][n][lane&15] = swa[n];
      sred[1][wr][wc][n][lane&15] = sw[n];
    }
  }
  __syncthreads();
  if (tid < 256){
    int wc2 = tid>>6, n2 = (tid>>4)&3, col = tid&15;
    float a = sred[0][0][wc2][n2][col] + sred[0][1][wc2][n2][col];
    float s = sred[1][0][wc2][n2][col] + sred[1][1][wc2][n2][col];
    sumWA[(size_t)b*NB + tid] = a;
    sumW [(size_t)b*NB + tid] = s;
  }
}

// ---------------- 32-iteration selection loop: single wave, zero barriers ----------------
__global__ __launch_bounds__(64) void loop_kernel(
    const float* __restrict__ img, const float* __restrict__ pl,
    const float* __restrict__ cs, const float* __restrict__ d0,
    const float* __restrict__ G, float* __restrict__ obj /* [NIT][NB][NC] */)
{
  const int b = blockIdx.x, lane = threadIdx.x;
  const float* imgb = img + (size_t)b*NC*NP;
  const float* Gb = G + (size_t)b*NP*NP;

  float plv[4], csL[4], d0v[4], gdd[4], posv[4];
  bool alr[4];
  #pragma unroll
  for (int s=0;s<4;++s){
    int p = lane + 64*s;
    bool valid = p < NP;
    plv[s] = valid ? pl[b*NP+p] : 0.f;
    csL[s] = valid ? plv[s]*cs[b*NP+p] : 0.f;
    d0v[s] = valid ? d0[b*NP+p] : 0.f;
    gdd[s] = valid ? Gb[(size_t)p*NP+p] : 0.f;
    posv[s] = valid ? plv[s] : -INFINITY;
    alr[s] = false;
  }
  bool endp = false;

  for (int t=0;t<NIT;++t){
    // argmax (first-occurrence)
    float v = posv[0]; int ix = lane;
    #pragma unroll
    for (int s=1;s<4;++s){
      if (posv[s] > v){ v = posv[s]; ix = lane + 64*s; }
    }
    #pragma unroll
    for (int m=1;m<64;m<<=1){
      float vv = __shfl_xor(v, m);
      int   ii = __shfl_xor(ix, m);
      if (vv>v || (vv==v && ii<ix)){ v=vv; ix=ii; }
    }
    const int q = ix;
    const int slot = q >> 6, ln = q & 63;
    float pq=0.f, gq=0.f, cq=0.f;
    #pragma unroll
    for (int s=0;s<4;++s){
      if (s==slot){ pq=plv[s]; gq=gdd[s]; cq=csL[s]; }
    }
    const float plq  = __shfl(pq, ln);
    const float gqq  = __shfl(gq, ln);
    const float csLq = __shfl(cq, ln);

    // obj[t][b][:]
    {
      float* op = obj + ((size_t)t*NB + b)*NC;
      #pragma unroll
      for (int j2=0;j2<8;++j2){
        int c = lane + 64*j2;
        op[c] = endp ? 0.0f : imgb[(size_t)c*NP + q]*plq;
      }
    }

    // pos detect via Gram expansion (double)
    int cnt = 0;
    #pragma unroll
    for (int s=0;s<4;++s){
      int p = lane + 64*s;
      if (p<NP && !alr[s]){
        float Gpq = Gb[(size_t)q*NP + p];
        double plp=(double)plv[s], dq=(double)plq;
        const double e=(double)1e-6f;
        double d2 = plp*plp*(double)gdd[s]
                  - 2.0*plp*dq*(double)Gpq
                  + dq*dq*(double)gqq
                  + 2.0*e*((double)csL[s]-(double)csLq)
                  + (double)NC*e*e;
        if (d2<0.0) d2=0.0;
        if (sqrt(d2) < (double)d0v[s]){ alr[s]=true; posv[s]=posv[s]*0.0f; cnt++; }
      }
    }
    float mx = fmaxf(fmaxf(posv[0],posv[1]),fmaxf(posv[2],posv[3]));
    #pragma unroll
    for (int m=1;m<64;m<<=1){
      cnt += __shfl_xor(cnt, m);
      mx = fmaxf(mx, __shfl_xor(mx, m));
    }
    if (cnt==0 || mx<0.1f) endp=true;
  }
}

// ---------------- loss ----------------
__global__ __launch_bounds__(256) void finalize_kernel(
    const float* __restrict__ sim1, const float* __restrict__ sim2,
    const float* __restrict__ sumWA, const float* __restrict__ sumW,
    float* __restrict__ out_loss)
{
  const int b = threadIdx.x;
  const float T = 0.07f;
  float l0 = sim1[b]/T;
  float ll = sim2[b]/T;
  float m = fmaxf(l0,ll);
  for (int k=0;k<NB;++k){
    float s = sumWA[(size_t)b*NB+k]/sumW[(size_t)b*NB+k];
    if (k==b) s *= -99.0f;
    m = fmaxf(m, s/T);
  }
  double se = exp((double)(l0-m)) + exp((double)(ll-m));
  for (int k=0;k<NB;++k){
    float s = sumWA[(size_t)b*NB+k]/sumW[(size_t)b*NB+k];
    if (k==b) s *= -99.0f;
    se += exp((double)(s/T-m));
  }
  float lsm0 = (float)((double)(l0-m) - log(se));
  __shared__ double s_redd[256];
  s_redd[b] = -(double)lsm0;
  __syncthreads();
  for (int s=128;s>0;s>>=1){ if (b<s) s_redd[b]+=s_redd[b+s]; __syncthreads(); }
  if (b==0) out_loss[0]=(float)(s_redd[0]/(double)NB);
}

extern "C" void kernel_launch(void* const* d_in, const int* in_sizes, int n_in,
                              void* d_out, int out_size, void* d_ws, size_t ws_size,
                              hipStream_t stream)
{
  const float* img = (const float*)d_in[0];
  const float* aud = (const float*)d_in[1];
  float* out = (float*)d_out;
  float* ws  = (float*)d_ws;

  // ws layout (floats)
  float* pl    = ws;                        // 50176
  float* cs    = pl    + NB*NP;             // 50176
  float* d0    = cs    + NB*NP;             // 50176
  float* sim1  = d0    + NB*NP;             // 256
  float* sim2  = sim1  + NB;                // 256
  float* sumWA = sim2  + NB;                // 65536
  float* sumW  = sumWA + NB*NB;             // 65536
  unsigned short* aud_bf = (unsigned short*)(sumW + NB*NB);  // 131072 ushorts
  float* G     = (float*)(aud_bf + NB*NC);  // 9,834,496 floats (~39.3 MB)

  float* out_loss = out;
  float* out_pl   = out + 1;
  float* out_obj  = out + 1 + NB*NP;

  hipLaunchKernelGGL(aud2bf_kernel,  dim3(NB*NC/256), dim3(256), 0, stream, aud, aud_bf);
  hipLaunchKernelGGL(prep_kernel,    dim3(NB),        dim3(256), 0, stream, img, aud, pl, cs, d0, sim1, sim2, out_pl);
  hipLaunchKernelGGL(gram_mfma,      dim3(NB),        dim3(512), 0, stream, img, G);
  hipLaunchKernelGGL(simgemm_mfma,   dim3(NB),        dim3(512), 0, stream, img, aud_bf, sumWA, sumW);
  hipLaunchKernelGGL(loop_kernel,    dim3(NB),        dim3(64),  0, stream, img, pl, cs, d0, G, out_obj);
  hipLaunchKernelGGL(finalize_kernel,dim3(1),         dim3(256), 0, stream, sim1, sim2, sumWA, sumW, out_loss);
}

// Round 4
// 388.939 us; speedup vs baseline: 1.9284x; 1.0768x over previous
//
#include <hip/hip_runtime.h>
#include <hip/hip_bf16.h>
#include <math.h>

#define NB 256
#define NC 512
#define NP 196
#define NIT 32
#define PROWS 208          // 13 tiles of 16

typedef __attribute__((ext_vector_type(8))) short bf16x8;
typedef __attribute__((ext_vector_type(4))) float f32x4;

__device__ __forceinline__ float sigf(float z){ return 1.0f/(1.0f+expf(-z)); }

__device__ __forceinline__ unsigned short f2bf(float x){
  return __bfloat16_as_ushort(__float2bfloat16(x));
}
__device__ __forceinline__ float bf2f(unsigned short h){
  union{float f; unsigned u;} v; v.u = ((unsigned)h)<<16; return v.f;
}
__device__ __forceinline__ double dshfl_xor(double v, int m){
  int lo = __shfl_xor(__double2loint(v), m);
  int hi = __shfl_xor(__double2hiint(v), m);
  return __hiloint2double(hi, lo);
}

// ---------------- aud -> bf16 ----------------
__global__ __launch_bounds__(256) void aud2bf_kernel(const float* __restrict__ aud, unsigned short* __restrict__ aud_bf)
{
  int i = blockIdx.x*256 + threadIdx.x;   // 131072
  aud_bf[i] = f2bf(aud[i]);
}

// ================= FAST PATH (needs ~150MB ws) =================

// ---------------- transpose+convert: img [b][c][p] fp32 -> imgT [b][208][512] bf16 hi & lo ----------------
#define SFSTR 211
__global__ __launch_bounds__(512) void convert_kernel(
    const float* __restrict__ img, unsigned short* __restrict__ hiT, unsigned short* __restrict__ loT)
{
  const int b = blockIdx.x, tid = threadIdx.x;
  const float* imgb = img + (size_t)b*NC*NP;
  __shared__ float sf[64*SFSTR];
  for (int sl=0; sl<8; ++sl){
    __syncthreads();
    for (int j=tid; j<64*49; j+=512){
      int p4 = j % 49, c = j / 49;
      float4 v = *(const float4*)&imgb[(size_t)(sl*64+c)*NP + p4*4];
      sf[c*SFSTR + p4*4+0]=v.x; sf[c*SFSTR + p4*4+1]=v.y;
      sf[c*SFSTR + p4*4+2]=v.z; sf[c*SFSTR + p4*4+3]=v.w;
    }
    __syncthreads();
    for (int j=tid; j<PROWS*8; j+=512){
      int p = j >> 3, cq = j & 7;
      unsigned hv[4], lv[4];
      #pragma unroll
      for (int k2=0;k2<4;++k2){
        float x0 = (p<NP) ? sf[(cq*8+2*k2  )*SFSTR + p] : 0.f;
        float x1 = (p<NP) ? sf[(cq*8+2*k2+1)*SFSTR + p] : 0.f;
        unsigned short h0=f2bf(x0), h1=f2bf(x1);
        unsigned short l0=f2bf(x0-bf2f(h0)), l1=f2bf(x1-bf2f(h1));
        hv[k2] = (unsigned)h0 | ((unsigned)h1<<16);
        lv[k2] = (unsigned)l0 | ((unsigned)l1<<16);
      }
      size_t o = ((size_t)b*PROWS + p)*NC + sl*64 + cq*8;
      *(uint4*)&hiT[o] = *(uint4*)hv;
      *(uint4*)&loT[o] = *(uint4*)lv;
    }
  }
}

// ---------------- prep from imgT: pl, cs, d0, sim1, sim2 ----------------
__global__ __launch_bounds__(512) void prep2_kernel(
    const unsigned short* __restrict__ hiT, const unsigned short* __restrict__ loT,
    const float* __restrict__ aud,
    float* __restrict__ pl, float* __restrict__ cs, float* __restrict__ d0,
    float* __restrict__ sim1, float* __restrict__ sim2, float* __restrict__ out_pl)
{
  const int b = blockIdx.x, tid = threadIdx.x;
  const int gid = tid >> 4, gl = tid & 15;
  const unsigned short* hb = hiT + (size_t)b*PROWS*NC;
  const unsigned short* lb = loT + (size_t)b*PROWS*NC;
  __shared__ float s_aud[NC];
  __shared__ float s_pl[NP];
  __shared__ float s_wl[NP];
  __shared__ float s_nv[NC];
  __shared__ double s_redd[512];
  if (tid < NC) s_aud[tid] = aud[b*NC + tid];
  __syncthreads();

  // Phase A: pl, cs per pixel row (16-lane groups, 32 rows concurrent)
  for (int p = gid; p < NP; p += 32){
    const unsigned short* hr = hb + (size_t)p*NC + gl*32;
    const unsigned short* lr = lb + (size_t)p*NC + gl*32;
    double a = 0.0, s = 0.0;
    #pragma unroll
    for (int q=0;q<4;++q){
      uint4 hv = *(const uint4*)(hr + q*8);
      uint4 lv = *(const uint4*)(lr + q*8);
      const unsigned* hw = (const unsigned*)&hv;
      const unsigned* lw = (const unsigned*)&lv;
      #pragma unroll
      for (int k2=0;k2<4;++k2){
        float x0 = bf2f((unsigned short)(hw[k2]&0xffff)) + bf2f((unsigned short)(lw[k2]&0xffff));
        float x1 = bf2f((unsigned short)(hw[k2]>>16))    + bf2f((unsigned short)(lw[k2]>>16));
        int c = gl*32 + q*8 + k2*2;
        a += (double)x0*(double)s_aud[c] + (double)x1*(double)s_aud[c+1];
        s += (double)x0 + (double)x1;
      }
    }
    #pragma unroll
    for (int m=1;m<16;m<<=1){ a += dshfl_xor(a,m); s += dshfl_xor(s,m); }
    if (gl==0){
      float plv=(float)a, csv=(float)s;
      pl[b*NP+p]=plv; cs[b*NP+p]=csv; out_pl[b*NP+p]=plv;
      s_pl[p]=plv;
      float negw = 1.0f - sigf((plv-0.40f)/0.03f);
      s_wl[p]=plv*negw;
    }
  }
  __syncthreads();

  // sims reductions
  float plv = (tid<NP)? s_pl[tid] : 0.f;
  float pmw = (tid<NP)? sigf((plv-0.65f)/0.03f) : 0.f;
  float negw= (tid<NP)? 1.0f - sigf((plv-0.40f)/0.03f) : 0.f;
  double r[4];
  r[0]=(tid<NP)?(double)pmw*(double)plv:0.0;
  r[1]=(tid<NP)?(double)pmw:0.0;
  r[2]=(tid<NP)?(double)negw*(double)plv:0.0;
  r[3]=(tid<NP)?(double)negw:0.0;
  double res[4];
  for (int i=0;i<4;++i){
    __syncthreads();
    s_redd[tid]=r[i];
    __syncthreads();
    for (int s=256;s>0;s>>=1){ if (tid<s) s_redd[tid]+=s_redd[tid+s]; __syncthreads(); }
    res[i]=s_redd[0];
  }
  if (tid==0){
    sim1[b]=(float)(res[0]/res[1]);
    sim2[b]=(float)(res[2]/res[3]);
  }
  __syncthreads();

  // Phase C: nv[c] (thread owns one channel)
  {
    double a=0.0;
    const unsigned short* hc = hb + tid;
    const unsigned short* lc = lb + tid;
    for (int p=0;p<NP;++p){
      float x = bf2f(hc[(size_t)p*NC]) + bf2f(lc[(size_t)p*NC]);
      a += (double)x*(double)s_wl[p];
    }
    s_nv[tid]=(float)(a/(double)NP);
  }
  __syncthreads();

  // Phase D: d0 per pixel row
  for (int p = gid; p < NP; p += 32){
    const unsigned short* hr = hb + (size_t)p*NC + gl*32;
    const unsigned short* lr = lb + (size_t)p*NC + gl*32;
    const double e=(double)1e-6f;
    double pld = (double)s_pl[p];
    double a = 0.0;
    #pragma unroll
    for (int q=0;q<4;++q){
      uint4 hv = *(const uint4*)(hr + q*8);
      uint4 lv = *(const uint4*)(lr + q*8);
      const unsigned* hw = (const unsigned*)&hv;
      const unsigned* lw = (const unsigned*)&lv;
      #pragma unroll
      for (int k2=0;k2<4;++k2){
        float x0 = bf2f((unsigned short)(hw[k2]&0xffff)) + bf2f((unsigned short)(lw[k2]&0xffff));
        float x1 = bf2f((unsigned short)(hw[k2]>>16))    + bf2f((unsigned short)(lw[k2]>>16));
        int c = gl*32 + q*8 + k2*2;
        double t0 = (double)x0*pld - (double)s_nv[c]   + e;
        double t1 = (double)x1*pld - (double)s_nv[c+1] + e;
        a += t0*t0 + t1*t1;
      }
    }
    #pragma unroll
    for (int m=1;m<16;m<<=1) a += dshfl_xor(a,m);
    if (gl==0) d0[b*NP+p]=(float)sqrt(a);
  }
}

// ---------------- Gram from imgT (split-bf16), 2 blocks per b ----------------
#define LSTR 72
__global__ __launch_bounds__(512) void gram2_kernel(
    const unsigned short* __restrict__ hiT, const unsigned short* __restrict__ loT,
    float* __restrict__ G)
{
  const int bid = blockIdx.x;
  const int b = bid >> 1, h = bid & 1;
  const int cbase = 7*h, ncl = 7 - h;          // col tiles: 0..6 / 7..12
  const int tid = threadIdx.x, lane = tid & 63, w = tid >> 6;
  const int nr = (w<5)?2:1;                     // row tiles: {w, w+8}
  const unsigned short* hb = hiT + (size_t)b*PROWS*NC;
  const unsigned short* lb = loT + (size_t)b*PROWS*NC;
  float* Gb = G + (size_t)b*NP*NP;
  __shared__ short smh[PROWS*LSTR];
  __shared__ short sml[PROWS*LSTR];

  f32x4 acc[2][7];
  #pragma unroll
  for (int i=0;i<2;++i)
    #pragma unroll
    for (int j=0;j<7;++j) acc[i][j]=(f32x4){0,0,0,0};

  for (int sl=0; sl<8; ++sl){
    __syncthreads();
    for (int j=tid; j<PROWS*8; j+=512){
      int p = j>>3, o = j&7;
      size_t src = (size_t)p*NC + sl*64 + o*8;
      uint4 hv = *(const uint4*)(hb + src);
      uint4 lv = *(const uint4*)(lb + src);
      *(uint4*)&smh[p*LSTR + o*8] = hv;
      *(uint4*)&sml[p*LSTR + o*8] = lv;
    }
    __syncthreads();
    #pragma unroll
    for (int kk=0; kk<2; ++kk){
      bf16x8 Ah[2], Al[2];
      #pragma unroll
      for (int i=0;i<2;++i){
        if (i<nr){
          int r = (w + 8*i)*16 + (lane&15);
          const short* pp = &smh[r*LSTR + kk*32 + (lane>>4)*8];
          Ah[i] = *(const bf16x8*)pp;
          Al[i] = *(const bf16x8*)&sml[r*LSTR + kk*32 + (lane>>4)*8];
        }
      }
      #pragma unroll
      for (int j=0;j<7;++j){
        if (j<ncl){
          int r = (cbase+j)*16 + (lane&15);
          bf16x8 Bh = *(const bf16x8*)&smh[r*LSTR + kk*32 + (lane>>4)*8];
          bf16x8 Bl = *(const bf16x8*)&sml[r*LSTR + kk*32 + (lane>>4)*8];
          #pragma unroll
          for (int i=0;i<2;++i){
            if (i<nr){
              acc[i][j] = __builtin_amdgcn_mfma_f32_16x16x32_bf16(Ah[i], Bh, acc[i][j], 0,0,0);
              acc[i][j] = __builtin_amdgcn_mfma_f32_16x16x32_bf16(Ah[i], Bl, acc[i][j], 0,0,0);
              acc[i][j] = __builtin_amdgcn_mfma_f32_16x16x32_bf16(Al[i], Bh, acc[i][j], 0,0,0);
            }
          }
        }
      }
    }
  }

  const int r0 = (lane>>4)*4, colL = lane & 15;
  #pragma unroll
  for (int i=0;i<2;++i){
    #pragma unroll
    for (int j=0;j<7;++j){
      if (i<nr && j<ncl){
        int row = (w+8*i)*16 + r0;
        int col = (cbase+j)*16 + colL;
        if (col < NP){
          #pragma unroll
          for (int jj=0;jj<4;++jj){
            if (row+jj < NP) Gb[(size_t)(row+jj)*NP + col] = acc[i][j][jj];
          }
        }
      }
    }
  }
}

// ---------------- all_logits GEMM + fused sigmoid sums, 2 blocks per b ----------------
__global__ __launch_bounds__(512) void simgemm2_kernel(
    const unsigned short* __restrict__ hiT, const unsigned short* __restrict__ aud_bf,
    float* __restrict__ sumWA, float* __restrict__ sumW)
{
  const int bid = blockIdx.x;
  const int b = bid >> 1, h = bid & 1;          // h: n-half (128 audio cols)
  const int tid = threadIdx.x, lane = tid & 63, w = tid >> 6;
  const int wr = w >> 2, wc = w & 3;            // 2 p-groups x 4 n-groups
  const int pbase = (wr==0)?0:7, npt = 7-wr;    // 7 / 6 p-tiles
  const unsigned short* hb = hiT + (size_t)b*PROWS*NC;
  __shared__ short smh[PROWS*LSTR];
  __shared__ short sma[128*LSTR];
  __shared__ float sred[2][2][4][2][16];

  f32x4 acc[7][2];
  #pragma unroll
  for (int i=0;i<7;++i)
    #pragma unroll
    for (int n=0;n<2;++n) acc[i][n]=(f32x4){0,0,0,0};

  for (int sl=0; sl<8; ++sl){
    __syncthreads();
    for (int j=tid; j<PROWS*8; j+=512){
      int p = j>>3, o = j&7;
      *(uint4*)&smh[p*LSTR + o*8] = *(const uint4*)(hb + (size_t)p*NC + sl*64 + o*8);
    }
    for (int j=tid; j<128*8; j+=512){
      int n = j>>3, o = j&7;
      *(uint4*)&sma[n*LSTR + o*8] = *(const uint4*)(aud_bf + (size_t)(h*128+n)*NC + sl*64 + o*8);
    }
    __syncthreads();
    #pragma unroll
    for (int kk=0; kk<2; ++kk){
      bf16x8 Ah[7];
      #pragma unroll
      for (int i=0;i<7;++i){
        if (i<npt){
          int r = (pbase+i)*16 + (lane&15);
          Ah[i] = *(const bf16x8*)&smh[r*LSTR + kk*32 + (lane>>4)*8];
        }
      }
      #pragma unroll
      for (int n=0;n<2;++n){
        int r = (wc*2+n)*16 + (lane&15);
        bf16x8 Bn = *(const bf16x8*)&sma[r*LSTR + kk*32 + (lane>>4)*8];
        #pragma unroll
        for (int i=0;i<7;++i)
          if (i<npt)
            acc[i][n] = __builtin_amdgcn_mfma_f32_16x16x32_bf16(Ah[i], Bn, acc[i][n], 0,0,0);
      }
    }
  }

  float swa[2]={0,0}, sw[2]={0,0};
  #pragma unroll
  for (int n=0;n<2;++n){
    #pragma unroll
    for (int i=0;i<7;++i){
      if (i<npt){
        int rowbase = (pbase+i)*16 + (lane>>4)*4;
        #pragma unroll
        for (int jj=0;jj<4;++jj){
          if (rowbase+jj < NP){
            float v = acc[i][n][jj];
            float wgt = sigf((v-0.65f)/0.03f);
            swa[n] += wgt*v; sw[n] += wgt;
          }
        }
      }
    }
  }
  #pragma unroll
  for (int n=0;n<2;++n){
    swa[n] += __shfl_xor(swa[n],16); swa[n] += __shfl_xor(swa[n],32);
    sw[n]  += __shfl_xor(sw[n],16);  sw[n]  += __shfl_xor(sw[n],32);
  }
  if (lane < 16){
    #pragma unroll
    for (int n=0;n<2;++n){
      sred[0][wr][wc][n][lane] = swa[n];
      sred[1][wr][wc][n][lane] = sw[n];
    }
  }
  __syncthreads();
  if (tid < 128){
    int wc2 = tid>>5, n2 = (tid>>4)&1, col = tid&15;
    float a = sred[0][0][wc2][n2][col] + sred[0][1][wc2][n2][col];
    float s = sred[1][0][wc2][n2][col] + sred[1][1][wc2][n2][col];
    int kcol = h*128 + (wc2*2+n2)*16 + col;
    sumWA[(size_t)b*NB + kcol] = a;
    sumW [(size_t)b*NB + kcol] = s;
  }
}

// ---------------- selection loop (single wave, obj from imgT rows) ----------------
__global__ __launch_bounds__(64) void loop2_kernel(
    const unsigned short* __restrict__ hiT, const unsigned short* __restrict__ loT,
    const float* __restrict__ pl, const float* __restrict__ cs, const float* __restrict__ d0,
    const float* __restrict__ G, float* __restrict__ obj)
{
  const int b = blockIdx.x, lane = threadIdx.x;
  const unsigned short* hb = hiT + (size_t)b*PROWS*NC;
  const unsigned short* lb = loT + (size_t)b*PROWS*NC;
  const float* Gb = G + (size_t)b*NP*NP;

  float plv[4], csL[4], d0v[4], gdd[4], posv[4];
  bool alr[4];
  #pragma unroll
  for (int s=0;s<4;++s){
    int p = lane + 64*s;
    bool valid = p < NP;
    plv[s] = valid ? pl[b*NP+p] : 0.f;
    csL[s] = valid ? plv[s]*cs[b*NP+p] : 0.f;
    d0v[s] = valid ? d0[b*NP+p] : 0.f;
    gdd[s] = valid ? Gb[(size_t)p*NP+p] : 0.f;
    posv[s] = valid ? plv[s] : -INFINITY;
    alr[s] = false;
  }
  bool endp = false;

  for (int t=0;t<NIT;++t){
    float v = posv[0]; int ix = lane;
    #pragma unroll
    for (int s=1;s<4;++s){
      if (posv[s] > v){ v = posv[s]; ix = lane + 64*s; }
    }
    #pragma unroll
    for (int m=1;m<64;m<<=1){
      float vv = __shfl_xor(v, m);
      int   ii = __shfl_xor(ix, m);
      if (vv>v || (vv==v && ii<ix)){ v=vv; ix=ii; }
    }
    const int q = ix;
    const int slot = q >> 6, ln = q & 63;
    float pq=0.f, gq=0.f, cq=0.f;
    #pragma unroll
    for (int s=0;s<4;++s){
      if (s==slot){ pq=plv[s]; gq=gdd[s]; cq=csL[s]; }
    }
    const float plq  = __shfl(pq, ln);
    const float gqq  = __shfl(gq, ln);
    const float csLq = __shfl(cq, ln);

    {
      float* op = obj + ((size_t)t*NB + b)*NC;
      uint4 hv = *(const uint4*)(hb + (size_t)q*NC + lane*8);
      uint4 lv = *(const uint4*)(lb + (size_t)q*NC + lane*8);
      const unsigned* hw = (const unsigned*)&hv;
      const unsigned* lw = (const unsigned*)&lv;
      float o8[8];
      #pragma unroll
      for (int k2=0;k2<4;++k2){
        float x0 = bf2f((unsigned short)(hw[k2]&0xffff)) + bf2f((unsigned short)(lw[k2]&0xffff));
        float x1 = bf2f((unsigned short)(hw[k2]>>16))    + bf2f((unsigned short)(lw[k2]>>16));
        o8[2*k2]   = endp ? 0.f : x0*plq;
        o8[2*k2+1] = endp ? 0.f : x1*plq;
      }
      *(float4*)&op[lane*8]   = *(float4*)&o8[0];
      *(float4*)&op[lane*8+4] = *(float4*)&o8[4];
    }

    int cnt = 0;
    #pragma unroll
    for (int s=0;s<4;++s){
      int p = lane + 64*s;
      if (p<NP && !alr[s]){
        float Gpq = Gb[(size_t)q*NP + p];
        double plp=(double)plv[s], dq=(double)plq;
        const double e=(double)1e-6f;
        double d2 = plp*plp*(double)gdd[s]
                  - 2.0*plp*dq*(double)Gpq
                  + dq*dq*(double)gqq
                  + 2.0*e*((double)csL[s]-(double)csLq)
                  + (double)NC*e*e;
        if (d2<0.0) d2=0.0;
        if (sqrt(d2) < (double)d0v[s]){ alr[s]=true; posv[s]=posv[s]*0.0f; cnt++; }
      }
    }
    float mx = fmaxf(fmaxf(posv[0],posv[1]),fmaxf(posv[2],posv[3]));
    #pragma unroll
    for (int m=1;m<64;m<<=1){
      cnt += __shfl_xor(cnt, m);
      mx = fmaxf(mx, __shfl_xor(mx, m));
    }
    if (cnt==0 || mx<0.1f) endp=true;
  }
}

// ================= FALLBACK PATH (R3, ~41MB ws) =================

__global__ __launch_bounds__(256) void prep_fb(
    const float* __restrict__ img, const float* __restrict__ aud,
    float* __restrict__ pl, float* __restrict__ cs, float* __restrict__ d0,
    float* __restrict__ sim1, float* __restrict__ sim2,
    float* __restrict__ out_pl)
{
  const int b = blockIdx.x, tid = threadIdx.x;
  const float* imgb = img + (size_t)b*NC*NP;
  __shared__ float s_aud[NC];
  __shared__ float s_wl[NP];
  __shared__ float s_nv[NC];
  __shared__ double s_redd[256];
  for (int c=tid;c<NC;c+=256) s_aud[c]=aud[b*NC+c];
  __syncthreads();
  float plv=0.f, pmw=0.f, negw=0.f;
  if (tid<NP){
    double a=0.0, s=0.0;
    for (int c=0;c<NC;++c){ float x=imgb[(size_t)c*NP+tid]; a += (double)x*(double)s_aud[c]; s += (double)x; }
    plv=(float)a;
    float csv=(float)s;
    pl[b*NP+tid]=plv; cs[b*NP+tid]=csv; out_pl[b*NP+tid]=plv;
    pmw  = sigf((plv-0.65f)/0.03f);
    negw = 1.0f - sigf((plv-0.40f)/0.03f);
    s_wl[tid]=plv*negw;
  }
  double r[4];
  r[0]=(tid<NP)?(double)pmw*(double)plv:0.0;
  r[1]=(tid<NP)?(double)pmw:0.0;
  r[2]=(tid<NP)?(double)negw*(double)plv:0.0;
  r[3]=(tid<NP)?(double)negw:0.0;
  double res[4];
  for (int i=0;i<4;++i){
    __syncthreads();
    s_redd[tid]=r[i];
    __syncthreads();
    for (int s=128;s>0;s>>=1){ if (tid<s) s_redd[tid]+=s_redd[tid+s]; __syncthreads(); }
    res[i]=s_redd[0];
  }
  if (tid==0){
    sim1[b]=(float)(res[0]/res[1]);
    sim2[b]=(float)(res[2]/res[3]);
  }
  __syncthreads();
  for (int c=tid;c<NC;c+=256){
    const float* row = imgb + (size_t)c*NP;
    double a=0.0;
    for (int p=0;p<NP;++p) a += (double)row[p]*(double)s_wl[p];
    s_nv[c]=(float)(a/(double)NP);
  }
  __syncthreads();
  if (tid<NP){
    double a=0.0;
    const double e=(double)1e-6f;
    for (int c=0;c<NC;++c){
      double t=(double)imgb[(size_t)c*NP+tid]*(double)plv - (double)s_nv[c] + e;
      a += t*t;
    }
    d0[b*NP+tid]=(float)sqrt(a);
  }
}

#define GKS 64
#define GSTR 72
#define SKS 128
#define SSTR 136

__device__ __forceinline__ bf16x8 frag_ld(const short* sm, int stride, int tile, int kk, int lane){
  int r = tile*16 + (lane & 15);
  int o = lane >> 4;
  const short* p = sm + r*stride + kk*32 + o*8;
  return *(const bf16x8*)p;
}

__global__ __launch_bounds__(512) void gram_fb(const float* __restrict__ img, float* __restrict__ G)
{
  const int b = blockIdx.x;
  const int tid = threadIdx.x, lane = tid & 63, w = tid >> 6;
  const int wr = w >> 1, wc = w & 1;
  const int rbase = (wr==0)?0:(3*wr+1), nr = (wr==0)?4:3;
  const int cbase = 7*wc, ncl = 7-wc;
  const float* imgb = img + (size_t)b*NC*NP;
  float* Gb = G + (size_t)b*NP*NP;
  __shared__ short smh[PROWS*GSTR];
  __shared__ short sml[PROWS*GSTR];

  f32x4 acc[4][7];
  #pragma unroll
  for (int i=0;i<4;++i)
    #pragma unroll
    for (int j=0;j<7;++j) acc[i][j] = (f32x4){0.f,0.f,0.f,0.f};

  for (int sl=0; sl<NC/GKS; ++sl){
    __syncthreads();
    #pragma unroll
    for (int it=0; it<4; ++it){
      int j = it*512 + tid;
      int p = j & 255, c8 = j >> 8;
      if (p < PROWS){
        float x[8];
        #pragma unroll
        for (int cc=0;cc<8;++cc){
          int c = sl*GKS + c8*8 + cc;
          x[cc] = (p<NP) ? imgb[(size_t)c*NP + p] : 0.f;
        }
        unsigned hw[4], lw[4];
        #pragma unroll
        for (int k2=0;k2<4;++k2){
          unsigned short h0=f2bf(x[2*k2]), h1=f2bf(x[2*k2+1]);
          float l0 = x[2*k2]-bf2f(h0), l1 = x[2*k2+1]-bf2f(h1);
          hw[k2] = (unsigned)h0 | ((unsigned)h1<<16);
          lw[k2] = (unsigned)f2bf(l0) | ((unsigned)f2bf(l1)<<16);
        }
        *(uint4*)&smh[p*GSTR + c8*8] = *(uint4*)hw;
        *(uint4*)&sml[p*GSTR + c8*8] = *(uint4*)lw;
      }
    }
    __syncthreads();
    #pragma unroll
    for (int kk=0; kk<GKS/32; ++kk){
      bf16x8 Ah[4], Al[4];
      #pragma unroll
      for (int i=0;i<4;++i){
        if (i<nr){ Ah[i]=frag_ld(smh,GSTR,rbase+i,kk,lane); Al[i]=frag_ld(sml,GSTR,rbase+i,kk,lane); }
      }
      #pragma unroll
      for (int j=0;j<7;++j){
        if (j<ncl){
          bf16x8 Bh = frag_ld(smh,GSTR,cbase+j,kk,lane);
          bf16x8 Bl = frag_ld(sml,GSTR,cbase+j,kk,lane);
          #pragma unroll
          for (int i=0;i<4;++i){
            if (i<nr){
              acc[i][j] = __builtin_amdgcn_mfma_f32_16x16x32_bf16(Ah[i], Bh, acc[i][j], 0,0,0);
              acc[i][j] = __builtin_amdgcn_mfma_f32_16x16x32_bf16(Ah[i], Bl, acc[i][j], 0,0,0);
              acc[i][j] = __builtin_amdgcn_mfma_f32_16x16x32_bf16(Al[i], Bh, acc[i][j], 0,0,0);
            }
          }
        }
      }
    }
  }

  const int r0 = (lane>>4)*4, colL = lane & 15;
  #pragma unroll
  for (int i=0;i<4;++i){
    #pragma unroll
    for (int j=0;j<7;++j){
      if (i<nr && j<ncl){
        int row = (rbase+i)*16 + r0;
        int col = (cbase+j)*16 + colL;
        if (col < NP){
          #pragma unroll
          for (int jj=0;jj<4;++jj){
            if (row+jj < NP) Gb[(size_t)(row+jj)*NP + col] = acc[i][j][jj];
          }
        }
      }
    }
  }
}

__global__ __launch_bounds__(512) void simgemm_fb(
    const float* __restrict__ img, const unsigned short* __restrict__ aud_bf,
    float* __restrict__ sumWA, float* __restrict__ sumW)
{
  const int b = blockIdx.x;
  const int tid = threadIdx.x, lane = tid & 63, w = tid >> 6;
  const int wr = w >> 2, wc = w & 3;
  const int pbase = (wr==0)?0:7, npt = 7-wr;
  const float* imgb = img + (size_t)b*NC*NP;
  __shared__ short smh[PROWS*SSTR];
  __shared__ float sred[2][2][4][4][16];

  f32x4 acc[7][4];
  #pragma unroll
  for (int i=0;i<7;++i)
    #pragma unroll
    for (int n=0;n<4;++n) acc[i][n] = (f32x4){0.f,0.f,0.f,0.f};

  for (int sl=0; sl<NC/SKS; ++sl){
    __syncthreads();
    #pragma unroll
    for (int it=0; it<8; ++it){
      int j = it*512 + tid;
      int p = j & 255, c8 = j >> 8;
      if (p < PROWS){
        float x[8];
        #pragma unroll
        for (int cc=0;cc<8;++cc){
          int c = sl*SKS + c8*8 + cc;
          x[cc] = (p<NP) ? imgb[(size_t)c*NP + p] : 0.f;
        }
        unsigned hw[4];
        #pragma unroll
        for (int k2=0;k2<4;++k2)
          hw[k2] = (unsigned)f2bf(x[2*k2]) | ((unsigned)f2bf(x[2*k2+1])<<16);
        *(uint4*)&smh[p*SSTR + c8*8] = *(uint4*)hw;
      }
    }
    __syncthreads();
    #pragma unroll
    for (int kk=0; kk<SKS/32; ++kk){
      bf16x8 Ah[7];
      #pragma unroll
      for (int i=0;i<7;++i)
        if (i<npt) Ah[i]=frag_ld(smh,SSTR,pbase+i,kk,lane);
      #pragma unroll
      for (int n=0;n<4;++n){
        int ntile = wc*4 + n;
        int k = ntile*16 + (lane&15);
        int c = sl*SKS + kk*32 + (lane>>4)*8;
        bf16x8 Bn = *(const bf16x8*)(aud_bf + (size_t)k*NC + c);
        #pragma unroll
        for (int i=0;i<7;++i)
          if (i<npt)
            acc[i][n] = __builtin_amdgcn_mfma_f32_16x16x32_bf16(Ah[i], Bn, acc[i][n], 0,0,0);
      }
    }
  }

  float swa[4]={0,0,0,0}, sw[4]={0,0,0,0};
  #pragma unroll
  for (int n=0;n<4;++n){
    #pragma unroll
    for (int i=0;i<7;++i){
      if (i<npt){
        int rowbase = (pbase+i)*16 + (lane>>4)*4;
        #pragma unroll
        for (int jj=0;jj<4;++jj){
          if (rowbase+jj < NP){
            float v = acc[i][n][jj];
            float wgt = sigf((v-0.65f)/0.03f);
            swa[n] += wgt*v; sw[n] += wgt;
          }
        }
      }
    }
  }
  #pragma unroll
  for (int n=0;n<4;++n){
    swa[n] += __shfl_xor(swa[n],16); swa[n] += __shfl_xor(swa[n],32);
    sw[n]  += __shfl_xor(sw[n],16);  sw[n]  += __shfl_xor(sw[n],32);
  }
  if (lane < 16){
    #pragma unroll
    for (int n=0;n<4;++n){
      sred[0][wr][wc][n][lane] = swa[n];
      sred[1][wr][wc][n][lane] = sw[n];
    }
  }
  __syncthreads();
  if (tid < 256){
    int wc2 = tid>>6, n2 = (tid>>4)&3, col = tid&15;
    float a = sred[0][0][wc2][n2][col] + sred[0][1][wc2][n2][col];
    float s = sred[1][0][wc2][n2][col] + sred[1][1][wc2][n2][col];
    sumWA[(size_t)b*NB + tid] = a;
    sumW [(size_t)b*NB + tid] = s;
  }
}

__global__ __launch_bounds__(64) void loop_fb(
    const float* __restrict__ img, const float* __restrict__ pl,
    const float* __restrict__ cs, const float* __restrict__ d0,
    const float* __restrict__ G, float* __restrict__ obj)
{
  const int b = blockIdx.x, lane = threadIdx.x;
  const float* imgb = img + (size_t)b*NC*NP;
  const float* Gb = G + (size_t)b*NP*NP;

  float plv[4], csL[4], d0v[4], gdd[4], posv[4];
  bool alr[4];
  #pragma unroll
  for (int s=0;s<4;++s){
    int p = lane + 64*s;
    bool valid = p < NP;
    plv[s] = valid ? pl[b*NP+p] : 0.f;
    csL[s] = valid ? plv[s]*cs[b*NP+p] : 0.f;
    d0v[s] = valid ? d0[b*NP+p] : 0.f;
    gdd[s] = valid ? Gb[(size_t)p*NP+p] : 0.f;
    posv[s] = valid ? plv[s] : -INFINITY;
    alr[s] = false;
  }
  bool endp = false;

  for (int t=0;t<NIT;++t){
    float v = posv[0]; int ix = lane;
    #pragma unroll
    for (int s=1;s<4;++s){
      if (posv[s] > v){ v = posv[s]; ix = lane + 64*s; }
    }
    #pragma unroll
    for (int m=1;m<64;m<<=1){
      float vv = __shfl_xor(v, m);
      int   ii = __shfl_xor(ix, m);
      if (vv>v || (vv==v && ii<ix)){ v=vv; ix=ii; }
    }
    const int q = ix;
    const int slot = q >> 6, ln = q & 63;
    float pq=0.f, gq=0.f, cq=0.f;
    #pragma unroll
    for (int s=0;s<4;++s){
      if (s==slot){ pq=plv[s]; gq=gdd[s]; cq=csL[s]; }
    }
    const float plq  = __shfl(pq, ln);
    const float gqq  = __shfl(gq, ln);
    const float csLq = __shfl(cq, ln);

    {
      float* op = obj + ((size_t)t*NB + b)*NC;
      #pragma unroll
      for (int j2=0;j2<8;++j2){
        int c = lane + 64*j2;
        op[c] = endp ? 0.0f : imgb[(size_t)c*NP + q]*plq;
      }
    }

    int cnt = 0;
    #pragma unroll
    for (int s=0;s<4;++s){
      int p = lane + 64*s;
      if (p<NP && !alr[s]){
        float Gpq = Gb[(size_t)q*NP + p];
        double plp=(double)plv[s], dq=(double)plq;
        const double e=(double)1e-6f;
        double d2 = plp*plp*(double)gdd[s]
                  - 2.0*plp*dq*(double)Gpq
                  + dq*dq*(double)gqq
                  + 2.0*e*((double)csL[s]-(double)csLq)
                  + (double)NC*e*e;
        if (d2<0.0) d2=0.0;
        if (sqrt(d2) < (double)d0v[s]){ alr[s]=true; posv[s]=posv[s]*0.0f; cnt++; }
      }
    }
    float mx = fmaxf(fmaxf(posv[0],posv[1]),fmaxf(posv[2],posv[3]));
    #pragma unroll
    for (int m=1;m<64;m<<=1){
      cnt += __shfl_xor(cnt, m);
      mx = fmaxf(mx, __shfl_xor(mx, m));
    }
    if (cnt==0 || mx<0.1f) endp=true;
  }
}

// ---------------- loss ----------------
__global__ __launch_bounds__(256) void finalize_kernel(
    const float* __restrict__ sim1, const float* __restrict__ sim2,
    const float* __restrict__ sumWA, const float* __restrict__ sumW,
    float* __restrict__ out_loss)
{
  const int b = threadIdx.x;
  const float T = 0.07f;
  float l0 = sim1[b]/T;
  float ll = sim2[b]/T;
  float m = fmaxf(l0,ll);
  for (int k=0;k<NB;++k){
    float s = sumWA[(size_t)b*NB+k]/sumW[(size_t)b*NB+k];
    if (k==b) s *= -99.0f;
    m = fmaxf(m, s/T);
  }
  double se = exp((double)(l0-m)) + exp((double)(ll-m));
  for (int k=0;k<NB;++k){
    float s = sumWA[(size_t)b*NB+k]/sumW[(size_t)b*NB+k];
    if (k==b) s *= -99.0f;
    se += exp((double)(s/T-m));
  }
  float lsm0 = (float)((double)(l0-m) - log(se));
  __shared__ double s_redd[256];
  s_redd[b] = -(double)lsm0;
  __syncthreads();
  for (int s=128;s>0;s>>=1){ if (b<s) s_redd[b]+=s_redd[b+s]; __syncthreads(); }
  if (b==0) out_loss[0]=(float)(s_redd[0]/(double)NB);
}

extern "C" void kernel_launch(void* const* d_in, const int* in_sizes, int n_in,
                              void* d_out, int out_size, void* d_ws, size_t ws_size,
                              hipStream_t stream)
{
  const float* img = (const float*)d_in[0];
  const float* aud = (const float*)d_in[1];
  float* out = (float*)d_out;
  float* ws  = (float*)d_ws;

  // ws layout (floats) — fast path appends imgT after the fallback-sized prefix
  float* pl    = ws;                        // 50176
  float* cs    = pl    + NB*NP;             // 50176
  float* d0    = cs    + NB*NP;             // 50176
  float* sim1  = d0    + NB*NP;             // 256
  float* sim2  = sim1  + NB;                // 256
  float* sumWA = sim2  + NB;                // 65536
  float* sumW  = sumWA + NB*NB;             // 65536
  unsigned short* aud_bf = (unsigned short*)(sumW + NB*NB);   // 131072 ushorts
  float* G     = (float*)(aud_bf + NB*NC);  // 9,834,496 floats
  unsigned short* hiT = (unsigned short*)(G + (size_t)NB*NP*NP);   // 27,262,976 ushorts
  unsigned short* loT = hiT + (size_t)NB*PROWS*NC;                 // 27,262,976 ushorts

  const size_t need_fast = (size_t)((char*)(loT + (size_t)NB*PROWS*NC) - (char*)ws);

  float* out_loss = out;
  float* out_pl   = out + 1;
  float* out_obj  = out + 1 + NB*NP;

  hipLaunchKernelGGL(aud2bf_kernel, dim3(NB*NC/256), dim3(256), 0, stream, aud, aud_bf);

  if (ws_size >= need_fast){
    hipLaunchKernelGGL(convert_kernel, dim3(NB),   dim3(512), 0, stream, img, hiT, loT);
    hipLaunchKernelGGL(prep2_kernel,   dim3(NB),   dim3(512), 0, stream, hiT, loT, aud, pl, cs, d0, sim1, sim2, out_pl);
    hipLaunchKernelGGL(gram2_kernel,   dim3(NB*2), dim3(512), 0, stream, hiT, loT, G);
    hipLaunchKernelGGL(simgemm2_kernel,dim3(NB*2), dim3(512), 0, stream, hiT, aud_bf, sumWA, sumW);
    hipLaunchKernelGGL(loop2_kernel,   dim3(NB),   dim3(64),  0, stream, hiT, loT, pl, cs, d0, G, out_obj);
  } else {
    hipLaunchKernelGGL(prep_fb,    dim3(NB), dim3(256), 0, stream, img, aud, pl, cs, d0, sim1, sim2, out_pl);
    hipLaunchKernelGGL(gram_fb,    dim3(NB), dim3(512), 0, stream, img, G);
    hipLaunchKernelGGL(simgemm_fb, dim3(NB), dim3(512), 0, stream, img, aud_bf, sumWA, sumW);
    hipLaunchKernelGGL(loop_fb,    dim3(NB), dim3(64),  0, stream, img, pl, cs, d0, G, out_obj);
  }
  hipLaunchKernelGGL(finalize_kernel, dim3(1), dim3(256), 0, stream, sim1, sim2, sumWA, sumW, out_loss);
}

// Round 5
// 235.096 us; speedup vs baseline: 3.1903x; 1.6544x over previous
//
#include <hip/hip_runtime.h>
#include <hip/hip_bf16.h>
#include <math.h>

#define NB 256
#define NC 512
#define NP 196
#define NIT 32
#define PROWS 208          // 13 tiles of 16

typedef __attribute__((ext_vector_type(8))) short bf16x8;
typedef __attribute__((ext_vector_type(4))) float f32x4;

__device__ __forceinline__ float sigf(float z){ return 1.0f/(1.0f+expf(-z)); }

__device__ __forceinline__ unsigned short f2bf(float x){
  return __bfloat16_as_ushort(__float2bfloat16(x));
}
__device__ __forceinline__ float bf2f(unsigned short h){
  union{float f; unsigned u;} v; v.u = ((unsigned)h)<<16; return v.f;
}
__device__ __forceinline__ double dshfl_xor(double v, int m){
  int lo = __shfl_xor(__double2loint(v), m);
  int hi = __shfl_xor(__double2hiint(v), m);
  return __hiloint2double(hi, lo);
}

// ---------------- aud -> bf16 ----------------
__global__ __launch_bounds__(256) void aud2bf_kernel(const float* __restrict__ aud, unsigned short* __restrict__ aud_bf)
{
  int i = blockIdx.x*256 + threadIdx.x;   // 131072
  aud_bf[i] = f2bf(aud[i]);
}

// ================= FAST PATH =================

// ---------------- transpose+convert: img [b][c][p] fp32 -> imgT [b][208][512] bf16 hi & lo ----------------
#define SFSTR 211
__global__ __launch_bounds__(512) void convert_kernel(
    const float* __restrict__ img, unsigned short* __restrict__ hiT, unsigned short* __restrict__ loT)
{
  const int b = blockIdx.x, tid = threadIdx.x;
  const float* imgb = img + (size_t)b*NC*NP;
  __shared__ float sf[64*SFSTR];
  for (int sl=0; sl<8; ++sl){
    __syncthreads();
    for (int j=tid; j<64*49; j+=512){
      int p4 = j % 49, c = j / 49;
      float4 v = *(const float4*)&imgb[(size_t)(sl*64+c)*NP + p4*4];
      sf[c*SFSTR + p4*4+0]=v.x; sf[c*SFSTR + p4*4+1]=v.y;
      sf[c*SFSTR + p4*4+2]=v.z; sf[c*SFSTR + p4*4+3]=v.w;
    }
    __syncthreads();
    for (int j=tid; j<PROWS*8; j+=512){
      int p = j >> 3, cq = j & 7;
      unsigned hv[4], lv[4];
      #pragma unroll
      for (int k2=0;k2<4;++k2){
        float x0 = (p<NP) ? sf[(cq*8+2*k2  )*SFSTR + p] : 0.f;
        float x1 = (p<NP) ? sf[(cq*8+2*k2+1)*SFSTR + p] : 0.f;
        unsigned short h0=f2bf(x0), h1=f2bf(x1);
        unsigned short l0=f2bf(x0-bf2f(h0)), l1=f2bf(x1-bf2f(h1));
        hv[k2] = (unsigned)h0 | ((unsigned)h1<<16);
        lv[k2] = (unsigned)l0 | ((unsigned)l1<<16);
      }
      size_t o = ((size_t)b*PROWS + p)*NC + sl*64 + cq*8;
      *(uint4*)&hiT[o] = *(uint4*)hv;
      *(uint4*)&loT[o] = *(uint4*)lv;
    }
  }
}

// ---------------- prep from imgT: pl, cs, sim1, sim2 (d0 now comes from G in loop3) ----------------
__global__ __launch_bounds__(512) void prep2_kernel(
    const unsigned short* __restrict__ hiT, const unsigned short* __restrict__ loT,
    const float* __restrict__ aud,
    float* __restrict__ pl, float* __restrict__ cs,
    float* __restrict__ sim1, float* __restrict__ sim2, float* __restrict__ out_pl)
{
  const int b = blockIdx.x, tid = threadIdx.x;
  const int gid = tid >> 4, gl = tid & 15;
  const unsigned short* hb = hiT + (size_t)b*PROWS*NC;
  const unsigned short* lb = loT + (size_t)b*PROWS*NC;
  __shared__ float s_aud[NC];
  __shared__ float s_pl[NP];
  __shared__ double s_redd[512];
  if (tid < NC) s_aud[tid] = aud[b*NC + tid];
  __syncthreads();

  // pl, cs per pixel row (16-lane groups, 32 rows concurrent)
  for (int p = gid; p < NP; p += 32){
    const unsigned short* hr = hb + (size_t)p*NC + gl*32;
    const unsigned short* lr = lb + (size_t)p*NC + gl*32;
    double a = 0.0, s = 0.0;
    #pragma unroll
    for (int q=0;q<4;++q){
      uint4 hv = *(const uint4*)(hr + q*8);
      uint4 lv = *(const uint4*)(lr + q*8);
      const unsigned* hw = (const unsigned*)&hv;
      const unsigned* lw = (const unsigned*)&lv;
      #pragma unroll
      for (int k2=0;k2<4;++k2){
        float x0 = bf2f((unsigned short)(hw[k2]&0xffff)) + bf2f((unsigned short)(lw[k2]&0xffff));
        float x1 = bf2f((unsigned short)(hw[k2]>>16))    + bf2f((unsigned short)(lw[k2]>>16));
        int c = gl*32 + q*8 + k2*2;
        a += (double)x0*(double)s_aud[c] + (double)x1*(double)s_aud[c+1];
        s += (double)x0 + (double)x1;
      }
    }
    #pragma unroll
    for (int m=1;m<16;m<<=1){ a += dshfl_xor(a,m); s += dshfl_xor(s,m); }
    if (gl==0){
      float plv=(float)a, csv=(float)s;
      pl[b*NP+p]=plv; cs[b*NP+p]=csv; out_pl[b*NP+p]=plv;
      s_pl[p]=plv;
    }
  }
  __syncthreads();

  // sims reductions
  float plv = (tid<NP)? s_pl[tid] : 0.f;
  float pmw = (tid<NP)? sigf((plv-0.65f)/0.03f) : 0.f;
  float negw= (tid<NP)? 1.0f - sigf((plv-0.40f)/0.03f) : 0.f;
  double r[4];
  r[0]=(tid<NP)?(double)pmw*(double)plv:0.0;
  r[1]=(tid<NP)?(double)pmw:0.0;
  r[2]=(tid<NP)?(double)negw*(double)plv:0.0;
  r[3]=(tid<NP)?(double)negw:0.0;
  double res[4];
  for (int i=0;i<4;++i){
    __syncthreads();
    s_redd[tid]=r[i];
    __syncthreads();
    for (int s=256;s>0;s>>=1){ if (tid<s) s_redd[tid]+=s_redd[tid+s]; __syncthreads(); }
    res[i]=s_redd[0];
  }
  if (tid==0){
    sim1[b]=(float)(res[0]/res[1]);
    sim2[b]=(float)(res[2]/res[3]);
  }
}

// ---------------- Gram from imgT (split-bf16), 2 blocks per b ----------------
#define LSTR 72
__global__ __launch_bounds__(512) void gram2_kernel(
    const unsigned short* __restrict__ hiT, const unsigned short* __restrict__ loT,
    float* __restrict__ G)
{
  const int bid = blockIdx.x;
  const int b = bid & 255, h = bid >> 8;        // pair (b, b+256) shares XCD
  const int cbase = 7*h, ncl = 7 - h;           // col tiles: 0..6 / 7..12
  const int tid = threadIdx.x, lane = tid & 63, w = tid >> 6;
  const int nr = (w<5)?2:1;                     // row tiles: {w, w+8}
  const unsigned short* hb = hiT + (size_t)b*PROWS*NC;
  const unsigned short* lb = loT + (size_t)b*PROWS*NC;
  float* Gb = G + (size_t)b*NP*NP;
  __shared__ short smh[PROWS*LSTR];
  __shared__ short sml[PROWS*LSTR];

  f32x4 acc[2][7];
  #pragma unroll
  for (int i=0;i<2;++i)
    #pragma unroll
    for (int j=0;j<7;++j) acc[i][j]=(f32x4){0,0,0,0};

  for (int sl=0; sl<8; ++sl){
    __syncthreads();
    for (int j=tid; j<PROWS*8; j+=512){
      int p = j>>3, o = j&7;
      size_t src = (size_t)p*NC + sl*64 + o*8;
      uint4 hv = *(const uint4*)(hb + src);
      uint4 lv = *(const uint4*)(lb + src);
      *(uint4*)&smh[p*LSTR + o*8] = hv;
      *(uint4*)&sml[p*LSTR + o*8] = lv;
    }
    __syncthreads();
    #pragma unroll
    for (int kk=0; kk<2; ++kk){
      bf16x8 Ah[2], Al[2];
      #pragma unroll
      for (int i=0;i<2;++i){
        if (i<nr){
          int r = (w + 8*i)*16 + (lane&15);
          Ah[i] = *(const bf16x8*)&smh[r*LSTR + kk*32 + (lane>>4)*8];
          Al[i] = *(const bf16x8*)&sml[r*LSTR + kk*32 + (lane>>4)*8];
        }
      }
      #pragma unroll
      for (int j=0;j<7;++j){
        if (j<ncl){
          int r = (cbase+j)*16 + (lane&15);
          bf16x8 Bh = *(const bf16x8*)&smh[r*LSTR + kk*32 + (lane>>4)*8];
          bf16x8 Bl = *(const bf16x8*)&sml[r*LSTR + kk*32 + (lane>>4)*8];
          #pragma unroll
          for (int i=0;i<2;++i){
            if (i<nr){
              acc[i][j] = __builtin_amdgcn_mfma_f32_16x16x32_bf16(Ah[i], Bh, acc[i][j], 0,0,0);
              acc[i][j] = __builtin_amdgcn_mfma_f32_16x16x32_bf16(Ah[i], Bl, acc[i][j], 0,0,0);
              acc[i][j] = __builtin_amdgcn_mfma_f32_16x16x32_bf16(Al[i], Bh, acc[i][j], 0,0,0);
            }
          }
        }
      }
    }
  }

  const int r0 = (lane>>4)*4, colL = lane & 15;
  #pragma unroll
  for (int i=0;i<2;++i){
    #pragma unroll
    for (int j=0;j<7;++j){
      if (i<nr && j<ncl){
        int row = (w+8*i)*16 + r0;
        int col = (cbase+j)*16 + colL;
        if (col < NP){
          #pragma unroll
          for (int jj=0;jj<4;++jj){
            if (row+jj < NP) Gb[(size_t)(row+jj)*NP + col] = acc[i][j][jj];
          }
        }
      }
    }
  }
}

// ---------------- all_logits GEMM + fused sigmoid sums, 2 blocks per b ----------------
__global__ __launch_bounds__(512) void simgemm2_kernel(
    const unsigned short* __restrict__ hiT, const unsigned short* __restrict__ aud_bf,
    float* __restrict__ sumWA, float* __restrict__ sumW)
{
  const int bid = blockIdx.x;
  const int b = bid & 255, h = bid >> 8;        // h: n-half (128 audio cols)
  const int tid = threadIdx.x, lane = tid & 63, w = tid >> 6;
  const int wr = w >> 2, wc = w & 3;            // 2 p-groups x 4 n-groups
  const int pbase = (wr==0)?0:7, npt = 7-wr;    // 7 / 6 p-tiles
  const unsigned short* hb = hiT + (size_t)b*PROWS*NC;
  __shared__ short smh[PROWS*LSTR];
  __shared__ short sma[128*LSTR];
  __shared__ float sred[2][2][4][2][16];

  f32x4 acc[7][2];
  #pragma unroll
  for (int i=0;i<7;++i)
    #pragma unroll
    for (int n=0;n<2;++n) acc[i][n]=(f32x4){0,0,0,0};

  for (int sl=0; sl<8; ++sl){
    __syncthreads();
    for (int j=tid; j<PROWS*8; j+=512){
      int p = j>>3, o = j&7;
      *(uint4*)&smh[p*LSTR + o*8] = *(const uint4*)(hb + (size_t)p*NC + sl*64 + o*8);
    }
    for (int j=tid; j<128*8; j+=512){
      int n = j>>3, o = j&7;
      *(uint4*)&sma[n*LSTR + o*8] = *(const uint4*)(aud_bf + (size_t)(h*128+n)*NC + sl*64 + o*8);
    }
    __syncthreads();
    #pragma unroll
    for (int kk=0; kk<2; ++kk){
      bf16x8 Ah[7];
      #pragma unroll
      for (int i=0;i<7;++i){
        if (i<npt){
          int r = (pbase+i)*16 + (lane&15);
          Ah[i] = *(const bf16x8*)&smh[r*LSTR + kk*32 + (lane>>4)*8];
        }
      }
      #pragma unroll
      for (int n=0;n<2;++n){
        int r = (wc*2+n)*16 + (lane&15);
        bf16x8 Bn = *(const bf16x8*)&sma[r*LSTR + kk*32 + (lane>>4)*8];
        #pragma unroll
        for (int i=0;i<7;++i)
          if (i<npt)
            acc[i][n] = __builtin_amdgcn_mfma_f32_16x16x32_bf16(Ah[i], Bn, acc[i][n], 0,0,0);
      }
    }
  }

  float swa[2]={0,0}, sw[2]={0,0};
  #pragma unroll
  for (int n=0;n<2;++n){
    #pragma unroll
    for (int i=0;i<7;++i){
      if (i<npt){
        int rowbase = (pbase+i)*16 + (lane>>4)*4;
        #pragma unroll
        for (int jj=0;jj<4;++jj){
          if (rowbase+jj < NP){
            float v = acc[i][n][jj];
            float wgt = sigf((v-0.65f)/0.03f);
            swa[n] += wgt*v; sw[n] += wgt;
          }
        }
      }
    }
  }
  #pragma unroll
  for (int n=0;n<2;++n){
    swa[n] += __shfl_xor(swa[n],16); swa[n] += __shfl_xor(swa[n],32);
    sw[n]  += __shfl_xor(sw[n],16);  sw[n]  += __shfl_xor(sw[n],32);
  }
  if (lane < 16){
    #pragma unroll
    for (int n=0;n<2;++n){
      sred[0][wr][wc][n][lane] = swa[n];
      sred[1][wr][wc][n][lane] = sw[n];
    }
  }
  __syncthreads();
  if (tid < 128){
    int wc2 = tid>>5, n2 = (tid>>4)&1, col = tid&15;
    float a = sred[0][0][wc2][n2][col] + sred[0][1][wc2][n2][col];
    float s = sred[1][0][wc2][n2][col] + sred[1][1][wc2][n2][col];
    int kcol = h*128 + (wc2*2+n2)*16 + col;
    sumWA[(size_t)b*NB + kcol] = a;
    sumW [(size_t)b*NB + kcol] = s;
  }
}

// ---------------- selection loop: G in LDS, serial wave, decisions only ----------------
__global__ __launch_bounds__(256) void loop3_kernel(
    const float* __restrict__ pl, const float* __restrict__ cs,
    const float* __restrict__ G, int* __restrict__ qseq, int* __restrict__ zf)
{
  const int b = blockIdx.x, tid = threadIdx.x, lane = tid & 63, w = tid >> 6;
  const float* Gb = G + (size_t)b*NP*NP;
  __shared__ float sG[NP*NP];                 // 153,664 B
  __shared__ float s_pl[NP], s_wl[NP], s_csL[NP], s_gd[NP];
  __shared__ double gwd[NP];
  __shared__ double s_redd[256];

  // stage G (flat memcpy, float4)
  #pragma unroll
  for (int k=0;k<38;++k){
    int j = k*256 + tid;
    if (j < NP*NP/4) ((float4*)sG)[j] = ((const float4*)Gb)[j];
  }
  float negw_t = 0.f;
  if (tid < NP){
    float plv = pl[b*NP+tid];
    float csv = cs[b*NP+tid];
    s_pl[tid] = plv;
    s_csL[tid] = plv*csv;
    negw_t = 1.0f - sigf((plv-0.40f)/0.03f);
    s_wl[tid] = plv*negw_t;
    s_gd[tid] = Gb[(size_t)tid*NP + tid];
  }
  __syncthreads();

  // gw_p = sum_q G[q][p] * wl[q]  (column access: conflict-free; G symmetric)
  double gw = 0.0;
  if (tid < NP){
    for (int q=0;q<NP;++q) gw += (double)sG[q*NP + tid] * (double)s_wl[q];
    gwd[tid] = gw;
  }
  // S2 = sum_p wl_p*gw_p ; Swl = sum_p wl_p*cs_p = negw_p * csL_p
  __syncthreads();
  s_redd[tid] = (tid<NP) ? (double)s_wl[tid]*gw : 0.0;
  __syncthreads();
  for (int st=128;st>0;st>>=1){ if (tid<st) s_redd[tid]+=s_redd[tid+st]; __syncthreads(); }
  const double S2 = s_redd[0];
  __syncthreads();
  s_redd[tid] = (tid<NP) ? (double)negw_t*(double)s_csL[tid] : 0.0;
  __syncthreads();
  for (int st=128;st>0;st>>=1){ if (tid<st) s_redd[tid]+=s_redd[tid+st]; __syncthreads(); }
  const double Swl = s_redd[0];
  __syncthreads();

  // d0^2 per pixel via Gram identity
  if (tid < NP){
    const double e = (double)1e-6f;
    double pld = (double)s_pl[tid];
    double d0sq = pld*pld*(double)s_gd[tid]
                - (2.0/196.0)*pld*gwd[tid]
                + S2/(196.0*196.0)
                + 2.0*e*((double)s_csL[tid] - Swl/196.0)
                + 512.0*e*e;
    if (d0sq < 0.0) d0sq = 0.0;
    gwd[tid] = d0sq;     // overwrite gw with d0sq (own slot)
  }
  __syncthreads();

  if (w != 0) return;   // serial part: wave 0 only (no barriers below)

  float plv[4], csL[4], gdd[4], posv[4];
  double d0sq[4];
  bool alr[4];
  #pragma unroll
  for (int s=0;s<4;++s){
    int p = lane + 64*s;
    bool valid = p < NP;
    plv[s]  = valid ? s_pl[p]  : 0.f;
    csL[s]  = valid ? s_csL[p] : 0.f;
    gdd[s]  = valid ? s_gd[p]  : 0.f;
    d0sq[s] = valid ? gwd[p]   : 0.0;
    posv[s] = valid ? plv[s]   : -INFINITY;
    alr[s] = false;
  }
  bool endp = false;

  for (int t=0;t<NIT;++t){
    float v = posv[0]; int ix = lane;
    #pragma unroll
    for (int s=1;s<4;++s){
      if (posv[s] > v){ v = posv[s]; ix = lane + 64*s; }
    }
    #pragma unroll
    for (int m=1;m<64;m<<=1){
      float vv = __shfl_xor(v, m);
      int   ii = __shfl_xor(ix, m);
      if (vv>v || (vv==v && ii<ix)){ v=vv; ix=ii; }
    }
    const int q = ix;
    const float plq  = s_pl[q];
    const float gqq  = s_gd[q];
    const float csLq = s_csL[q];
    if (lane==0){ qseq[b*NIT+t] = q; zf[b*NIT+t] = endp ? 1 : 0; }

    int cnt = 0;
    #pragma unroll
    for (int s=0;s<4;++s){
      int p = lane + 64*s;
      if (p<NP && !alr[s]){
        float Gpq = sG[q*NP + p];
        double plp=(double)plv[s], dq=(double)plq;
        const double e=(double)1e-6f;
        double d2 = plp*plp*(double)gdd[s]
                  - 2.0*plp*dq*(double)Gpq
                  + dq*dq*(double)gqq
                  + 2.0*e*((double)csL[s]-(double)csLq)
                  + 512.0*e*e;
        if (d2<0.0) d2=0.0;
        if (d2 < d0sq[s]){ alr[s]=true; posv[s]=posv[s]*0.0f; cnt++; }
      }
    }
    float mx = fmaxf(fmaxf(posv[0],posv[1]),fmaxf(posv[2],posv[3]));
    #pragma unroll
    for (int m=1;m<64;m<<=1){
      cnt += __shfl_xor(cnt, m);
      mx = fmaxf(mx, __shfl_xor(mx, m));
    }
    if (cnt==0 || mx<0.1f) endp=true;
  }
}

// ---------------- parallel obj writer ----------------
__global__ __launch_bounds__(64) void objw_kernel(
    const unsigned short* __restrict__ hiT, const unsigned short* __restrict__ loT,
    const float* __restrict__ pl, const int* __restrict__ qseq, const int* __restrict__ zf,
    float* __restrict__ obj)
{
  const int bid = blockIdx.x;
  const int b = bid >> 5, t = bid & 31;     // NIT = 32
  const int lane = threadIdx.x;
  float* op = obj + ((size_t)t*NB + b)*NC;
  const int z = zf[b*NIT + t];
  if (z){
    float4 zv = {0.f,0.f,0.f,0.f};
    *(float4*)&op[lane*8]   = zv;
    *(float4*)&op[lane*8+4] = zv;
    return;
  }
  const int q = qseq[b*NIT + t];
  const float plq = pl[b*NP + q];
  size_t src = ((size_t)b*PROWS + q)*NC + lane*8;
  uint4 hv = *(const uint4*)(hiT + src);
  uint4 lv = *(const uint4*)(loT + src);
  const unsigned* hw = (const unsigned*)&hv;
  const unsigned* lw = (const unsigned*)&lv;
  float o8[8];
  #pragma unroll
  for (int k2=0;k2<4;++k2){
    float x0 = bf2f((unsigned short)(hw[k2]&0xffff)) + bf2f((unsigned short)(lw[k2]&0xffff));
    float x1 = bf2f((unsigned short)(hw[k2]>>16))    + bf2f((unsigned short)(lw[k2]>>16));
    o8[2*k2]   = x0*plq;
    o8[2*k2+1] = x1*plq;
  }
  *(float4*)&op[lane*8]   = *(float4*)&o8[0];
  *(float4*)&op[lane*8+4] = *(float4*)&o8[4];
}

// ---------------- loss: per-b block, then sum ----------------
__global__ __launch_bounds__(256) void finalize_b(
    const float* __restrict__ sim1, const float* __restrict__ sim2,
    const float* __restrict__ sumWA, const float* __restrict__ sumW,
    float* __restrict__ lossb)
{
  const int b = blockIdx.x, k = threadIdx.x;
  __shared__ float s_red[256];
  __shared__ double s_redd[256];
  const float T = 0.07f;
  float s = sumWA[(size_t)b*NB+k]/sumW[(size_t)b*NB+k];
  if (k==b) s *= -99.0f;
  const float lk = s/T;
  const float l0 = sim1[b]/T, ll = sim2[b]/T;
  s_red[k]=lk; __syncthreads();
  for (int st=128;st>0;st>>=1){ if(k<st) s_red[k]=fmaxf(s_red[k],s_red[k+st]); __syncthreads(); }
  const float m = fmaxf(s_red[0], fmaxf(l0,ll));
  __syncthreads();
  double e = (double)expf(lk-m);
  if (k==0) e += (double)expf(l0-m)+(double)expf(ll-m);
  s_redd[k]=e; __syncthreads();
  for (int st=128;st>0;st>>=1){ if(k<st) s_redd[k]+=s_redd[k+st]; __syncthreads(); }
  if (k==0) lossb[b] = -(float)((double)(l0-m) - log(s_redd[0]));
}

__global__ __launch_bounds__(256) void finalize_sum(const float* __restrict__ lossb, float* __restrict__ out_loss)
{
  const int tid = threadIdx.x;
  __shared__ double sr[256];
  sr[tid]=(double)lossb[tid]; __syncthreads();
  for (int st=128;st>0;st>>=1){ if(tid<st) sr[tid]+=sr[tid+st]; __syncthreads(); }
  if (tid==0) out_loss[0]=(float)(sr[0]/256.0);
}

// ================= FALLBACK PATH (R3, ~41MB ws) =================

__global__ __launch_bounds__(256) void prep_fb(
    const float* __restrict__ img, const float* __restrict__ aud,
    float* __restrict__ pl, float* __restrict__ cs, float* __restrict__ d0,
    float* __restrict__ sim1, float* __restrict__ sim2,
    float* __restrict__ out_pl)
{
  const int b = blockIdx.x, tid = threadIdx.x;
  const float* imgb = img + (size_t)b*NC*NP;
  __shared__ float s_aud[NC];
  __shared__ float s_wl[NP];
  __shared__ float s_nv[NC];
  __shared__ double s_redd[256];
  for (int c=tid;c<NC;c+=256) s_aud[c]=aud[b*NC+c];
  __syncthreads();
  float plv=0.f, pmw=0.f, negw=0.f;
  if (tid<NP){
    double a=0.0, s=0.0;
    for (int c=0;c<NC;++c){ float x=imgb[(size_t)c*NP+tid]; a += (double)x*(double)s_aud[c]; s += (double)x; }
    plv=(float)a;
    float csv=(float)s;
    pl[b*NP+tid]=plv; cs[b*NP+tid]=csv; out_pl[b*NP+tid]=plv;
    pmw  = sigf((plv-0.65f)/0.03f);
    negw = 1.0f - sigf((plv-0.40f)/0.03f);
    s_wl[tid]=plv*negw;
  }
  double r[4];
  r[0]=(tid<NP)?(double)pmw*(double)plv:0.0;
  r[1]=(tid<NP)?(double)pmw:0.0;
  r[2]=(tid<NP)?(double)negw*(double)plv:0.0;
  r[3]=(tid<NP)?(double)negw:0.0;
  double res[4];
  for (int i=0;i<4;++i){
    __syncthreads();
    s_redd[tid]=r[i];
    __syncthreads();
    for (int s=128;s>0;s>>=1){ if (tid<s) s_redd[tid]+=s_redd[tid+s]; __syncthreads(); }
    res[i]=s_redd[0];
  }
  if (tid==0){
    sim1[b]=(float)(res[0]/res[1]);
    sim2[b]=(float)(res[2]/res[3]);
  }
  __syncthreads();
  for (int c=tid;c<NC;c+=256){
    const float* row = imgb + (size_t)c*NP;
    double a=0.0;
    for (int p=0;p<NP;++p) a += (double)row[p]*(double)s_wl[p];
    s_nv[c]=(float)(a/(double)NP);
  }
  __syncthreads();
  if (tid<NP){
    double a=0.0;
    const double e=(double)1e-6f;
    for (int c=0;c<NC;++c){
      double t=(double)imgb[(size_t)c*NP+tid]*(double)plv - (double)s_nv[c] + e;
      a += t*t;
    }
    d0[b*NP+tid]=(float)sqrt(a);
  }
}

#define GKS 64
#define GSTR 72
#define SKS 128
#define SSTR 136

__device__ __forceinline__ bf16x8 frag_ld(const short* sm, int stride, int tile, int kk, int lane){
  int r = tile*16 + (lane & 15);
  int o = lane >> 4;
  const short* p = sm + r*stride + kk*32 + o*8;
  return *(const bf16x8*)p;
}

__global__ __launch_bounds__(512) void gram_fb(const float* __restrict__ img, float* __restrict__ G)
{
  const int b = blockIdx.x;
  const int tid = threadIdx.x, lane = tid & 63, w = tid >> 6;
  const int wr = w >> 1, wc = w & 1;
  const int rbase = (wr==0)?0:(3*wr+1), nr = (wr==0)?4:3;
  const int cbase = 7*wc, ncl = 7-wc;
  const float* imgb = img + (size_t)b*NC*NP;
  float* Gb = G + (size_t)b*NP*NP;
  __shared__ short smh[PROWS*GSTR];
  __shared__ short sml[PROWS*GSTR];

  f32x4 acc[4][7];
  #pragma unroll
  for (int i=0;i<4;++i)
    #pragma unroll
    for (int j=0;j<7;++j) acc[i][j] = (f32x4){0.f,0.f,0.f,0.f};

  for (int sl=0; sl<NC/GKS; ++sl){
    __syncthreads();
    #pragma unroll
    for (int it=0; it<4; ++it){
      int j = it*512 + tid;
      int p = j & 255, c8 = j >> 8;
      if (p < PROWS){
        float x[8];
        #pragma unroll
        for (int cc=0;cc<8;++cc){
          int c = sl*GKS + c8*8 + cc;
          x[cc] = (p<NP) ? imgb[(size_t)c*NP + p] : 0.f;
        }
        unsigned hw[4], lw[4];
        #pragma unroll
        for (int k2=0;k2<4;++k2){
          unsigned short h0=f2bf(x[2*k2]), h1=f2bf(x[2*k2+1]);
          float l0 = x[2*k2]-bf2f(h0), l1 = x[2*k2+1]-bf2f(h1);
          hw[k2] = (unsigned)h0 | ((unsigned)h1<<16);
          lw[k2] = (unsigned)f2bf(l0) | ((unsigned)f2bf(l1)<<16);
        }
        *(uint4*)&smh[p*GSTR + c8*8] = *(uint4*)hw;
        *(uint4*)&sml[p*GSTR + c8*8] = *(uint4*)lw;
      }
    }
    __syncthreads();
    #pragma unroll
    for (int kk=0; kk<GKS/32; ++kk){
      bf16x8 Ah[4], Al[4];
      #pragma unroll
      for (int i=0;i<4;++i){
        if (i<nr){ Ah[i]=frag_ld(smh,GSTR,rbase+i,kk,lane); Al[i]=frag_ld(sml,GSTR,rbase+i,kk,lane); }
      }
      #pragma unroll
      for (int j=0;j<7;++j){
        if (j<ncl){
          bf16x8 Bh = frag_ld(smh,GSTR,cbase+j,kk,lane);
          bf16x8 Bl = frag_ld(sml,GSTR,cbase+j,kk,lane);
          #pragma unroll
          for (int i=0;i<4;++i){
            if (i<nr){
              acc[i][j] = __builtin_amdgcn_mfma_f32_16x16x32_bf16(Ah[i], Bh, acc[i][j], 0,0,0);
              acc[i][j] = __builtin_amdgcn_mfma_f32_16x16x32_bf16(Ah[i], Bl, acc[i][j], 0,0,0);
              acc[i][j] = __builtin_amdgcn_mfma_f32_16x16x32_bf16(Al[i], Bh, acc[i][j], 0,0,0);
            }
          }
        }
      }
    }
  }

  const int r0 = (lane>>4)*4, colL = lane & 15;
  #pragma unroll
  for (int i=0;i<4;++i){
    #pragma unroll
    for (int j=0;j<7;++j){
      if (i<nr && j<ncl){
        int row = (rbase+i)*16 + r0;
        int col = (cbase+j)*16 + colL;
        if (col < NP){
          #pragma unroll
          for (int jj=0;jj<4;++jj){
            if (row+jj < NP) Gb[(size_t)(row+jj)*NP + col] = acc[i][j][jj];
          }
        }
      }
    }
  }
}

__global__ __launch_bounds__(512) void simgemm_fb(
    const float* __restrict__ img, const unsigned short* __restrict__ aud_bf,
    float* __restrict__ sumWA, float* __restrict__ sumW)
{
  const int b = blockIdx.x;
  const int tid = threadIdx.x, lane = tid & 63, w = tid >> 6;
  const int wr = w >> 2, wc = w & 3;
  const int pbase = (wr==0)?0:7, npt = 7-wr;
  const float* imgb = img + (size_t)b*NC*NP;
  __shared__ short smh[PROWS*SSTR];
  __shared__ float sred[2][2][4][4][16];

  f32x4 acc[7][4];
  #pragma unroll
  for (int i=0;i<7;++i)
    #pragma unroll
    for (int n=0;n<4;++n) acc[i][n] = (f32x4){0.f,0.f,0.f,0.f};

  for (int sl=0; sl<NC/SKS; ++sl){
    __syncthreads();
    #pragma unroll
    for (int it=0; it<8; ++it){
      int j = it*512 + tid;
      int p = j & 255, c8 = j >> 8;
      if (p < PROWS){
        float x[8];
        #pragma unroll
        for (int cc=0;cc<8;++cc){
          int c = sl*SKS + c8*8 + cc;
          x[cc] = (p<NP) ? imgb[(size_t)c*NP + p] : 0.f;
        }
        unsigned hw[4];
        #pragma unroll
        for (int k2=0;k2<4;++k2)
          hw[k2] = (unsigned)f2bf(x[2*k2]) | ((unsigned)f2bf(x[2*k2+1])<<16);
        *(uint4*)&smh[p*SSTR + c8*8] = *(uint4*)hw;
      }
    }
    __syncthreads();
    #pragma unroll
    for (int kk=0; kk<SKS/32; ++kk){
      bf16x8 Ah[7];
      #pragma unroll
      for (int i=0;i<7;++i)
        if (i<npt) Ah[i]=frag_ld(smh,SSTR,pbase+i,kk,lane);
      #pragma unroll
      for (int n=0;n<4;++n){
        int ntile = wc*4 + n;
        int k = ntile*16 + (lane&15);
        int c = sl*SKS + kk*32 + (lane>>4)*8;
        bf16x8 Bn = *(const bf16x8*)(aud_bf + (size_t)k*NC + c);
        #pragma unroll
        for (int i=0;i<7;++i)
          if (i<npt)
            acc[i][n] = __builtin_amdgcn_mfma_f32_16x16x32_bf16(Ah[i], Bn, acc[i][n], 0,0,0);
      }
    }
  }

  float swa[4]={0,0,0,0}, sw[4]={0,0,0,0};
  #pragma unroll
  for (int n=0;n<4;++n){
    #pragma unroll
    for (int i=0;i<7;++i){
      if (i<npt){
        int rowbase = (pbase+i)*16 + (lane>>4)*4;
        #pragma unroll
        for (int jj=0;jj<4;++jj){
          if (rowbase+jj < NP){
            float v = acc[i][n][jj];
            float wgt = sigf((v-0.65f)/0.03f);
            swa[n] += wgt*v; sw[n] += wgt;
          }
        }
      }
    }
  }
  #pragma unroll
  for (int n=0;n<4;++n){
    swa[n] += __shfl_xor(swa[n],16); swa[n] += __shfl_xor(swa[n],32);
    sw[n]  += __shfl_xor(sw[n],16);  sw[n]  += __shfl_xor(sw[n],32);
  }
  if (lane < 16){
    #pragma unroll
    for (int n=0;n<4;++n){
      sred[0][wr][wc][n][lane] = swa[n];
      sred[1][wr][wc][n][lane] = sw[n];
    }
  }
  __syncthreads();
  if (tid < 256){
    int wc2 = tid>>6, n2 = (tid>>4)&3, col = tid&15;
    float a = sred[0][0][wc2][n2][col] + sred[0][1][wc2][n2][col];
    float s = sred[1][0][wc2][n2][col] + sred[1][1][wc2][n2][col];
    sumWA[(size_t)b*NB + tid] = a;
    sumW [(size_t)b*NB + tid] = s;
  }
}

__global__ __launch_bounds__(64) void loop_fb(
    const float* __restrict__ img, const float* __restrict__ pl,
    const float* __restrict__ cs, const float* __restrict__ d0,
    const float* __restrict__ G, float* __restrict__ obj)
{
  const int b = blockIdx.x, lane = threadIdx.x;
  const float* imgb = img + (size_t)b*NC*NP;
  const float* Gb = G + (size_t)b*NP*NP;

  float plv[4], csL[4], d0v[4], gdd[4], posv[4];
  bool alr[4];
  #pragma unroll
  for (int s=0;s<4;++s){
    int p = lane + 64*s;
    bool valid = p < NP;
    plv[s] = valid ? pl[b*NP+p] : 0.f;
    csL[s] = valid ? plv[s]*cs[b*NP+p] : 0.f;
    d0v[s] = valid ? d0[b*NP+p] : 0.f;
    gdd[s] = valid ? Gb[(size_t)p*NP+p] : 0.f;
    posv[s] = valid ? plv[s] : -INFINITY;
    alr[s] = false;
  }
  bool endp = false;

  for (int t=0;t<NIT;++t){
    float v = posv[0]; int ix = lane;
    #pragma unroll
    for (int s=1;s<4;++s){
      if (posv[s] > v){ v = posv[s]; ix = lane + 64*s; }
    }
    #pragma unroll
    for (int m=1;m<64;m<<=1){
      float vv = __shfl_xor(v, m);
      int   ii = __shfl_xor(ix, m);
      if (vv>v || (vv==v && ii<ix)){ v=vv; ix=ii; }
    }
    const int q = ix;
    const int slot = q >> 6, ln = q & 63;
    float pq=0.f, gq=0.f, cq=0.f;
    #pragma unroll
    for (int s=0;s<4;++s){
      if (s==slot){ pq=plv[s]; gq=gdd[s]; cq=csL[s]; }
    }
    const float plq  = __shfl(pq, ln);
    const float gqq  = __shfl(gq, ln);
    const float csLq = __shfl(cq, ln);

    {
      float* op = obj + ((size_t)t*NB + b)*NC;
      #pragma unroll
      for (int j2=0;j2<8;++j2){
        int c = lane + 64*j2;
        op[c] = endp ? 0.0f : imgb[(size_t)c*NP + q]*plq;
      }
    }

    int cnt = 0;
    #pragma unroll
    for (int s=0;s<4;++s){
      int p = lane + 64*s;
      if (p<NP && !alr[s]){
        float Gpq = Gb[(size_t)q*NP + p];
        double plp=(double)plv[s], dq=(double)plq;
        const double e=(double)1e-6f;
        double d2 = plp*plp*(double)gdd[s]
                  - 2.0*plp*dq*(double)Gpq
                  + dq*dq*(double)gqq
                  + 2.0*e*((double)csL[s]-(double)csLq)
                  + (double)NC*e*e;
        if (d2<0.0) d2=0.0;
        if (sqrt(d2) < (double)d0v[s]){ alr[s]=true; posv[s]=posv[s]*0.0f; cnt++; }
      }
    }
    float mx = fmaxf(fmaxf(posv[0],posv[1]),fmaxf(posv[2],posv[3]));
    #pragma unroll
    for (int m=1;m<64;m<<=1){
      cnt += __shfl_xor(cnt, m);
      mx = fmaxf(mx, __shfl_xor(mx, m));
    }
    if (cnt==0 || mx<0.1f) endp=true;
  }
}

__global__ __launch_bounds__(256) void finalize_fb(
    const float* __restrict__ sim1, const float* __restrict__ sim2,
    const float* __restrict__ sumWA, const float* __restrict__ sumW,
    float* __restrict__ out_loss)
{
  const int b = threadIdx.x;
  const float T = 0.07f;
  float l0 = sim1[b]/T;
  float ll = sim2[b]/T;
  float m = fmaxf(l0,ll);
  for (int k=0;k<NB;++k){
    float s = sumWA[(size_t)b*NB+k]/sumW[(size_t)b*NB+k];
    if (k==b) s *= -99.0f;
    m = fmaxf(m, s/T);
  }
  double se = exp((double)(l0-m)) + exp((double)(ll-m));
  for (int k=0;k<NB;++k){
    float s = sumWA[(size_t)b*NB+k]/sumW[(size_t)b*NB+k];
    if (k==b) s *= -99.0f;
    se += exp((double)(s/T-m));
  }
  float lsm0 = (float)((double)(l0-m) - log(se));
  __shared__ double s_redd[256];
  s_redd[b] = -(double)lsm0;
  __syncthreads();
  for (int s=128;s>0;s>>=1){ if (b<s) s_redd[b]+=s_redd[b+s]; __syncthreads(); }
  if (b==0) out_loss[0]=(float)(s_redd[0]/(double)NB);
}

extern "C" void kernel_launch(void* const* d_in, const int* in_sizes, int n_in,
                              void* d_out, int out_size, void* d_ws, size_t ws_size,
                              hipStream_t stream)
{
  const float* img = (const float*)d_in[0];
  const float* aud = (const float*)d_in[1];
  float* out = (float*)d_out;
  float* ws  = (float*)d_ws;

  // ws layout (floats)
  float* pl    = ws;                        // 50176
  float* cs    = pl    + NB*NP;             // 50176
  float* d0    = cs    + NB*NP;             // 50176 (fallback only)
  float* sim1  = d0    + NB*NP;             // 256
  float* sim2  = sim1  + NB;                // 256
  float* sumWA = sim2  + NB;                // 65536
  float* sumW  = sumWA + NB*NB;             // 65536
  unsigned short* aud_bf = (unsigned short*)(sumW + NB*NB);   // 131072 ushorts
  float* G     = (float*)(aud_bf + NB*NC);  // 9,834,496 floats
  unsigned short* hiT = (unsigned short*)(G + (size_t)NB*NP*NP);
  unsigned short* loT = hiT + (size_t)NB*PROWS*NC;
  int* qseq    = (int*)(loT + (size_t)NB*PROWS*NC);           // 8192 ints
  int* zf      = qseq + NB*NIT;                               // 8192 ints
  float* lossb = (float*)(zf + NB*NIT);                       // 256 floats

  const size_t need_fast = (size_t)((char*)(lossb + NB) - (char*)ws);

  float* out_loss = out;
  float* out_pl   = out + 1;
  float* out_obj  = out + 1 + NB*NP;

  hipLaunchKernelGGL(aud2bf_kernel, dim3(NB*NC/256), dim3(256), 0, stream, aud, aud_bf);

  if (ws_size >= need_fast){
    hipLaunchKernelGGL(convert_kernel, dim3(NB),     dim3(512), 0, stream, img, hiT, loT);
    hipLaunchKernelGGL(prep2_kernel,   dim3(NB),     dim3(512), 0, stream, hiT, loT, aud, pl, cs, sim1, sim2, out_pl);
    hipLaunchKernelGGL(gram2_kernel,   dim3(NB*2),   dim3(512), 0, stream, hiT, loT, G);
    hipLaunchKernelGGL(simgemm2_kernel,dim3(NB*2),   dim3(512), 0, stream, hiT, aud_bf, sumWA, sumW);
    hipLaunchKernelGGL(loop3_kernel,   dim3(NB),     dim3(256), 0, stream, pl, cs, G, qseq, zf);
    hipLaunchKernelGGL(objw_kernel,    dim3(NB*NIT), dim3(64),  0, stream, hiT, loT, pl, qseq, zf, out_obj);
    hipLaunchKernelGGL(finalize_b,     dim3(NB),     dim3(256), 0, stream, sim1, sim2, sumWA, sumW, lossb);
    hipLaunchKernelGGL(finalize_sum,   dim3(1),      dim3(256), 0, stream, lossb, out_loss);
  } else {
    hipLaunchKernelGGL(prep_fb,    dim3(NB), dim3(256), 0, stream, img, aud, pl, cs, d0, sim1, sim2, out_pl);
    hipLaunchKernelGGL(gram_fb,    dim3(NB), dim3(512), 0, stream, img, G);
    hipLaunchKernelGGL(simgemm_fb, dim3(NB), dim3(512), 0, stream, img, aud_bf, sumWA, sumW);
    hipLaunchKernelGGL(loop_fb,    dim3(NB), dim3(64),  0, stream, img, pl, cs, d0, G, out_obj);
    hipLaunchKernelGGL(finalize_fb,dim3(1),  dim3(256), 0, stream, sim1, sim2, sumWA, sumW, out_loss);
  }
}

// Round 6
// 211.630 us; speedup vs baseline: 3.5441x; 1.1109x over previous
//
#include <hip/hip_runtime.h>
#include <hip/hip_bf16.h>
#include <math.h>

#define NB 256
#define NC 512
#define NP 196
#define NIT 32
#define PROWS 208          // 13 tiles of 16

typedef __attribute__((ext_vector_type(8))) short bf16x8;
typedef __attribute__((ext_vector_type(4))) float f32x4;

__device__ __forceinline__ float sigf(float z){ return 1.0f/(1.0f+expf(-z)); }

__device__ __forceinline__ unsigned short f2bf(float x){
  return __bfloat16_as_ushort(__float2bfloat16(x));
}
__device__ __forceinline__ float bf2f(unsigned short h){
  union{float f; unsigned u;} v; v.u = ((unsigned)h)<<16; return v.f;
}
__device__ __forceinline__ double dshfl_xor(double v, int m){
  int lo = __shfl_xor(__double2loint(v), m);
  int hi = __shfl_xor(__double2hiint(v), m);
  return __hiloint2double(hi, lo);
}

// ---------------- aud -> bf16 ----------------
__global__ __launch_bounds__(256) void aud2bf_kernel(const float* __restrict__ aud, unsigned short* __restrict__ aud_bf)
{
  int i = blockIdx.x*256 + threadIdx.x;   // 131072
  aud_bf[i] = f2bf(aud[i]);
}

// ================= FAST PATH =================

// ---------------- transpose+convert+partial-pl: grid NB*4, 32-c sub-slices ----------------
#define SFSTR 211
__global__ __launch_bounds__(512) void convert3_kernel(
    const float* __restrict__ img, const float* __restrict__ aud,
    unsigned short* __restrict__ hiT, unsigned short* __restrict__ loT,
    double* __restrict__ ppl, double* __restrict__ pcs)   // [NB][4][196]
{
  const int bid = blockIdx.x;
  const int b = bid & 255, part = bid >> 8;     // all 4 parts of b on same XCD (256%8==0)
  const int tid = threadIdx.x;
  const float* imgb = img + (size_t)b*NC*NP;
  __shared__ float sf[32*SFSTR];                // 27.0 KB
  __shared__ double s_dp[PROWS], s_ds[PROWS];   // 3.3 KB
  __shared__ float s_aud[128];
  if (tid < 128) s_aud[tid] = aud[b*NC + part*128 + tid];
  for (int i=tid;i<PROWS;i+=512){ s_dp[i]=0.0; s_ds[i]=0.0; }

  for (int ss=0; ss<4; ++ss){
    const int c0 = part*128 + ss*32;
    __syncthreads();                            // protect sf reuse + init
    for (int j=tid; j<32*49; j+=512){
      int p4 = j % 49, c = j / 49;
      float4 v = *(const float4*)&imgb[(size_t)(c0+c)*NP + p4*4];
      sf[c*SFSTR + p4*4+0]=v.x; sf[c*SFSTR + p4*4+1]=v.y;
      sf[c*SFSTR + p4*4+2]=v.z; sf[c*SFSTR + p4*4+3]=v.w;
    }
    __syncthreads();
    for (int j=tid; j<PROWS*4; j+=512){
      int p = j >> 2, cq = j & 3;               // cq: 8-c group within the 32
      unsigned hv[4], lv[4];
      double dot=0.0, sm=0.0;
      #pragma unroll
      for (int k2=0;k2<4;++k2){
        float x0 = (p<NP) ? sf[(cq*8+2*k2  )*SFSTR + p] : 0.f;
        float x1 = (p<NP) ? sf[(cq*8+2*k2+1)*SFSTR + p] : 0.f;
        unsigned short h0=f2bf(x0), h1=f2bf(x1);
        unsigned short l0=f2bf(x0-bf2f(h0)), l1=f2bf(x1-bf2f(h1));
        hv[k2] = (unsigned)h0 | ((unsigned)h1<<16);
        lv[k2] = (unsigned)l0 | ((unsigned)l1<<16);
        int ca = ss*32 + cq*8 + 2*k2;           // index into s_aud (within part)
        dot += (double)x0*(double)s_aud[ca] + (double)x1*(double)s_aud[ca+1];
        sm  += (double)x0 + (double)x1;
      }
      size_t o = ((size_t)b*PROWS + p)*NC + c0 + cq*8;
      *(uint4*)&hiT[o] = *(uint4*)hv;
      *(uint4*)&loT[o] = *(uint4*)lv;
      // reduce the 4 cq-groups (lanes differing in low 2 bits)
      dot += dshfl_xor(dot,1); dot += dshfl_xor(dot,2);
      sm  += dshfl_xor(sm,1);  sm  += dshfl_xor(sm,2);
      if (cq==0 && p<NP){ s_dp[p] += dot; s_ds[p] += sm; }
    }
  }
  __syncthreads();
  for (int i=tid;i<NP;i+=512){
    ppl[((size_t)b*4 + part)*NP + i] = s_dp[i];
    pcs[((size_t)b*4 + part)*NP + i] = s_ds[i];
  }
}

// ---------------- prep3: reduce partials -> pl, cs, sims ----------------
__global__ __launch_bounds__(256) void prep3_kernel(
    const double* __restrict__ ppl, const double* __restrict__ pcs,
    float* __restrict__ pl, float* __restrict__ cs,
    float* __restrict__ sim1, float* __restrict__ sim2, float* __restrict__ out_pl)
{
  const int b = blockIdx.x, tid = threadIdx.x;
  __shared__ double s_redd[256];
  float plv=0.f;
  if (tid < NP){
    double a=0.0, s=0.0;
    #pragma unroll
    for (int part=0; part<4; ++part){
      a += ppl[((size_t)b*4+part)*NP + tid];
      s += pcs[((size_t)b*4+part)*NP + tid];
    }
    plv=(float)a;
    float csv=(float)s;
    pl[b*NP+tid]=plv; cs[b*NP+tid]=csv; out_pl[b*NP+tid]=plv;
  }
  float pmw = (tid<NP)? sigf((plv-0.65f)/0.03f) : 0.f;
  float negw= (tid<NP)? 1.0f - sigf((plv-0.40f)/0.03f) : 0.f;
  double r[4];
  r[0]=(tid<NP)?(double)pmw*(double)plv:0.0;
  r[1]=(tid<NP)?(double)pmw:0.0;
  r[2]=(tid<NP)?(double)negw*(double)plv:0.0;
  r[3]=(tid<NP)?(double)negw:0.0;
  double res[4];
  for (int i=0;i<4;++i){
    __syncthreads();
    s_redd[tid]=r[i];
    __syncthreads();
    for (int s=128;s>0;s>>=1){ if (tid<s) s_redd[tid]+=s_redd[tid+s]; __syncthreads(); }
    res[i]=s_redd[0];
  }
  if (tid==0){
    sim1[b]=(float)(res[0]/res[1]);
    sim2[b]=(float)(res[2]/res[3]);
  }
}

// ---------------- Gram from imgT (split-bf16), 2 blocks per b ----------------
#define LSTR 72
__global__ __launch_bounds__(512) void gram2_kernel(
    const unsigned short* __restrict__ hiT, const unsigned short* __restrict__ loT,
    float* __restrict__ G)
{
  const int bid = blockIdx.x;
  const int b = bid & 255, h = bid >> 8;        // pair (b, b+256) shares XCD
  const int cbase = 7*h, ncl = 7 - h;           // col tiles: 0..6 / 7..12
  const int tid = threadIdx.x, lane = tid & 63, w = tid >> 6;
  const int nr = (w<5)?2:1;                     // row tiles: {w, w+8}
  const unsigned short* hb = hiT + (size_t)b*PROWS*NC;
  const unsigned short* lb = loT + (size_t)b*PROWS*NC;
  float* Gb = G + (size_t)b*NP*NP;
  __shared__ short smh[PROWS*LSTR];
  __shared__ short sml[PROWS*LSTR];

  f32x4 acc[2][7];
  #pragma unroll
  for (int i=0;i<2;++i)
    #pragma unroll
    for (int j=0;j<7;++j) acc[i][j]=(f32x4){0,0,0,0};

  for (int sl=0; sl<8; ++sl){
    __syncthreads();
    for (int j=tid; j<PROWS*8; j+=512){
      int p = j>>3, o = j&7;
      size_t src = (size_t)p*NC + sl*64 + o*8;
      uint4 hv = *(const uint4*)(hb + src);
      uint4 lv = *(const uint4*)(lb + src);
      *(uint4*)&smh[p*LSTR + o*8] = hv;
      *(uint4*)&sml[p*LSTR + o*8] = lv;
    }
    __syncthreads();
    #pragma unroll
    for (int kk=0; kk<2; ++kk){
      bf16x8 Ah[2], Al[2];
      #pragma unroll
      for (int i=0;i<2;++i){
        if (i<nr){
          int r = (w + 8*i)*16 + (lane&15);
          Ah[i] = *(const bf16x8*)&smh[r*LSTR + kk*32 + (lane>>4)*8];
          Al[i] = *(const bf16x8*)&sml[r*LSTR + kk*32 + (lane>>4)*8];
        }
      }
      #pragma unroll
      for (int j=0;j<7;++j){
        if (j<ncl){
          int r = (cbase+j)*16 + (lane&15);
          bf16x8 Bh = *(const bf16x8*)&smh[r*LSTR + kk*32 + (lane>>4)*8];
          bf16x8 Bl = *(const bf16x8*)&sml[r*LSTR + kk*32 + (lane>>4)*8];
          #pragma unroll
          for (int i=0;i<2;++i){
            if (i<nr){
              acc[i][j] = __builtin_amdgcn_mfma_f32_16x16x32_bf16(Ah[i], Bh, acc[i][j], 0,0,0);
              acc[i][j] = __builtin_amdgcn_mfma_f32_16x16x32_bf16(Ah[i], Bl, acc[i][j], 0,0,0);
              acc[i][j] = __builtin_amdgcn_mfma_f32_16x16x32_bf16(Al[i], Bh, acc[i][j], 0,0,0);
            }
          }
        }
      }
    }
  }

  const int r0 = (lane>>4)*4, colL = lane & 15;
  #pragma unroll
  for (int i=0;i<2;++i){
    #pragma unroll
    for (int j=0;j<7;++j){
      if (i<nr && j<ncl){
        int row = (w+8*i)*16 + r0;
        int col = (cbase+j)*16 + colL;
        if (col < NP){
          #pragma unroll
          for (int jj=0;jj<4;++jj){
            if (row+jj < NP) Gb[(size_t)(row+jj)*NP + col] = acc[i][j][jj];
          }
        }
      }
    }
  }
}

// ---------------- all_logits GEMM + fused sigmoid sums, 2 blocks per b ----------------
__global__ __launch_bounds__(512) void simgemm2_kernel(
    const unsigned short* __restrict__ hiT, const unsigned short* __restrict__ aud_bf,
    float* __restrict__ sumWA, float* __restrict__ sumW)
{
  const int bid = blockIdx.x;
  const int b = bid & 255, h = bid >> 8;        // h: n-half (128 audio cols)
  const int tid = threadIdx.x, lane = tid & 63, w = tid >> 6;
  const int wr = w >> 2, wc = w & 3;            // 2 p-groups x 4 n-groups
  const int pbase = (wr==0)?0:7, npt = 7-wr;    // 7 / 6 p-tiles
  const unsigned short* hb = hiT + (size_t)b*PROWS*NC;
  __shared__ short smh[PROWS*LSTR];
  __shared__ short sma[128*LSTR];
  __shared__ float sred[2][2][4][2][16];

  f32x4 acc[7][2];
  #pragma unroll
  for (int i=0;i<7;++i)
    #pragma unroll
    for (int n=0;n<2;++n) acc[i][n]=(f32x4){0,0,0,0};

  for (int sl=0; sl<8; ++sl){
    __syncthreads();
    for (int j=tid; j<PROWS*8; j+=512){
      int p = j>>3, o = j&7;
      *(uint4*)&smh[p*LSTR + o*8] = *(const uint4*)(hb + (size_t)p*NC + sl*64 + o*8);
    }
    for (int j=tid; j<128*8; j+=512){
      int n = j>>3, o = j&7;
      *(uint4*)&sma[n*LSTR + o*8] = *(const uint4*)(aud_bf + (size_t)(h*128+n)*NC + sl*64 + o*8);
    }
    __syncthreads();
    #pragma unroll
    for (int kk=0; kk<2; ++kk){
      bf16x8 Ah[7];
      #pragma unroll
      for (int i=0;i<7;++i){
        if (i<npt){
          int r = (pbase+i)*16 + (lane&15);
          Ah[i] = *(const bf16x8*)&smh[r*LSTR + kk*32 + (lane>>4)*8];
        }
      }
      #pragma unroll
      for (int n=0;n<2;++n){
        int r = (wc*2+n)*16 + (lane&15);
        bf16x8 Bn = *(const bf16x8*)&sma[r*LSTR + kk*32 + (lane>>4)*8];
        #pragma unroll
        for (int i=0;i<7;++i)
          if (i<npt)
            acc[i][n] = __builtin_amdgcn_mfma_f32_16x16x32_bf16(Ah[i], Bn, acc[i][n], 0,0,0);
      }
    }
  }

  float swa[2]={0,0}, sw[2]={0,0};
  #pragma unroll
  for (int n=0;n<2;++n){
    #pragma unroll
    for (int i=0;i<7;++i){
      if (i<npt){
        int rowbase = (pbase+i)*16 + (lane>>4)*4;
        #pragma unroll
        for (int jj=0;jj<4;++jj){
          if (rowbase+jj < NP){
            float v = acc[i][n][jj];
            float wgt = sigf((v-0.65f)/0.03f);
            swa[n] += wgt*v; sw[n] += wgt;
          }
        }
      }
    }
  }
  #pragma unroll
  for (int n=0;n<2;++n){
    swa[n] += __shfl_xor(swa[n],16); swa[n] += __shfl_xor(swa[n],32);
    sw[n]  += __shfl_xor(sw[n],16);  sw[n]  += __shfl_xor(sw[n],32);
  }
  if (lane < 16){
    #pragma unroll
    for (int n=0;n<2;++n){
      sred[0][wr][wc][n][lane] = swa[n];
      sred[1][wr][wc][n][lane] = sw[n];
    }
  }
  __syncthreads();
  if (tid < 128){
    int wc2 = tid>>5, n2 = (tid>>4)&1, col = tid&15;
    float a = sred[0][0][wc2][n2][col] + sred[0][1][wc2][n2][col];
    float s = sred[1][0][wc2][n2][col] + sred[1][1][wc2][n2][col];
    int kcol = h*128 + (wc2*2+n2)*16 + col;
    sumWA[(size_t)b*NB + kcol] = a;
    sumW [(size_t)b*NB + kcol] = s;
  }
}

// ---------------- selection loop: G in LDS, serial wave, decisions only ----------------
__global__ __launch_bounds__(256) void loop3_kernel(
    const float* __restrict__ pl, const float* __restrict__ cs,
    const float* __restrict__ G, int* __restrict__ qseq, int* __restrict__ zf)
{
  const int b = blockIdx.x, tid = threadIdx.x, lane = tid & 63, w = tid >> 6;
  const float* Gb = G + (size_t)b*NP*NP;
  __shared__ float sG[NP*NP];                 // 153,664 B
  __shared__ float s_pl[NP], s_wl[NP], s_csL[NP], s_gd[NP];
  __shared__ double gwd[NP];
  __shared__ double s_redd[256];

  // stage G (flat memcpy, float4)
  #pragma unroll
  for (int k=0;k<38;++k){
    int j = k*256 + tid;
    if (j < NP*NP/4) ((float4*)sG)[j] = ((const float4*)Gb)[j];
  }
  float negw_t = 0.f;
  if (tid < NP){
    float plv = pl[b*NP+tid];
    float csv = cs[b*NP+tid];
    s_pl[tid] = plv;
    s_csL[tid] = plv*csv;
    negw_t = 1.0f - sigf((plv-0.40f)/0.03f);
    s_wl[tid] = plv*negw_t;
    s_gd[tid] = Gb[(size_t)tid*NP + tid];
  }
  __syncthreads();

  // gw_p = sum_q G[q][p] * wl[q]
  double gw = 0.0;
  if (tid < NP){
    for (int q=0;q<NP;++q) gw += (double)sG[q*NP + tid] * (double)s_wl[q];
    gwd[tid] = gw;
  }
  __syncthreads();
  s_redd[tid] = (tid<NP) ? (double)s_wl[tid]*gw : 0.0;
  __syncthreads();
  for (int st=128;st>0;st>>=1){ if (tid<st) s_redd[tid]+=s_redd[tid+st]; __syncthreads(); }
  const double S2 = s_redd[0];
  __syncthreads();
  s_redd[tid] = (tid<NP) ? (double)negw_t*(double)s_csL[tid] : 0.0;
  __syncthreads();
  for (int st=128;st>0;st>>=1){ if (tid<st) s_redd[tid]+=s_redd[tid+st]; __syncthreads(); }
  const double Swl = s_redd[0];
  __syncthreads();

  if (tid < NP){
    const double e = (double)1e-6f;
    double pld = (double)s_pl[tid];
    double d0sq = pld*pld*(double)s_gd[tid]
                - (2.0/196.0)*pld*gwd[tid]
                + S2/(196.0*196.0)
                + 2.0*e*((double)s_csL[tid] - Swl/196.0)
                + 512.0*e*e;
    if (d0sq < 0.0) d0sq = 0.0;
    gwd[tid] = d0sq;
  }
  __syncthreads();

  if (w != 0) return;   // serial part: wave 0 only

  float plv[4], csL[4], gdd[4], posv[4];
  double d0sq[4];
  bool alr[4];
  #pragma unroll
  for (int s=0;s<4;++s){
    int p = lane + 64*s;
    bool valid = p < NP;
    plv[s]  = valid ? s_pl[p]  : 0.f;
    csL[s]  = valid ? s_csL[p] : 0.f;
    gdd[s]  = valid ? s_gd[p]  : 0.f;
    d0sq[s] = valid ? gwd[p]   : 0.0;
    posv[s] = valid ? plv[s]   : -INFINITY;
    alr[s] = false;
  }
  bool endp = false;

  for (int t=0;t<NIT;++t){
    float v = posv[0]; int ix = lane;
    #pragma unroll
    for (int s=1;s<4;++s){
      if (posv[s] > v){ v = posv[s]; ix = lane + 64*s; }
    }
    #pragma unroll
    for (int m=1;m<64;m<<=1){
      float vv = __shfl_xor(v, m);
      int   ii = __shfl_xor(ix, m);
      if (vv>v || (vv==v && ii<ix)){ v=vv; ix=ii; }
    }
    const int q = ix;
    const float plq  = s_pl[q];
    const float gqq  = s_gd[q];
    const float csLq = s_csL[q];
    if (lane==0){ qseq[b*NIT+t] = q; zf[b*NIT+t] = endp ? 1 : 0; }

    int cnt = 0;
    #pragma unroll
    for (int s=0;s<4;++s){
      int p = lane + 64*s;
      if (p<NP && !alr[s]){
        float Gpq = sG[q*NP + p];
        double plp=(double)plv[s], dq=(double)plq;
        const double e=(double)1e-6f;
        double d2 = plp*plp*(double)gdd[s]
                  - 2.0*plp*dq*(double)Gpq
                  + dq*dq*(double)gqq
                  + 2.0*e*((double)csL[s]-(double)csLq)
                  + 512.0*e*e;
        if (d2<0.0) d2=0.0;
        if (d2 < d0sq[s]){ alr[s]=true; posv[s]=posv[s]*0.0f; cnt++; }
      }
    }
    float mx = fmaxf(fmaxf(posv[0],posv[1]),fmaxf(posv[2],posv[3]));
    #pragma unroll
    for (int m=1;m<64;m<<=1){
      cnt += __shfl_xor(cnt, m);
      mx = fmaxf(mx, __shfl_xor(mx, m));
    }
    if (cnt==0 || mx<0.1f) endp=true;
  }
}

// ---------------- parallel obj writer ----------------
__global__ __launch_bounds__(64) void objw_kernel(
    const unsigned short* __restrict__ hiT, const unsigned short* __restrict__ loT,
    const float* __restrict__ pl, const int* __restrict__ qseq, const int* __restrict__ zf,
    float* __restrict__ obj)
{
  const int bid = blockIdx.x;
  const int b = bid >> 5, t = bid & 31;     // NIT = 32
  const int lane = threadIdx.x;
  float* op = obj + ((size_t)t*NB + b)*NC;
  const int z = zf[b*NIT + t];
  if (z){
    float4 zv = {0.f,0.f,0.f,0.f};
    *(float4*)&op[lane*8]   = zv;
    *(float4*)&op[lane*8+4] = zv;
    return;
  }
  const int q = qseq[b*NIT + t];
  const float plq = pl[b*NP + q];
  size_t src = ((size_t)b*PROWS + q)*NC + lane*8;
  uint4 hv = *(const uint4*)(hiT + src);
  uint4 lv = *(const uint4*)(loT + src);
  const unsigned* hw = (const unsigned*)&hv;
  const unsigned* lw = (const unsigned*)&lv;
  float o8[8];
  #pragma unroll
  for (int k2=0;k2<4;++k2){
    float x0 = bf2f((unsigned short)(hw[k2]&0xffff)) + bf2f((unsigned short)(lw[k2]&0xffff));
    float x1 = bf2f((unsigned short)(hw[k2]>>16))    + bf2f((unsigned short)(lw[k2]>>16));
    o8[2*k2]   = x0*plq;
    o8[2*k2+1] = x1*plq;
  }
  *(float4*)&op[lane*8]   = *(float4*)&o8[0];
  *(float4*)&op[lane*8+4] = *(float4*)&o8[4];
}

// ---------------- loss: per-b block, then sum ----------------
__global__ __launch_bounds__(256) void finalize_b(
    const float* __restrict__ sim1, const float* __restrict__ sim2,
    const float* __restrict__ sumWA, const float* __restrict__ sumW,
    float* __restrict__ lossb)
{
  const int b = blockIdx.x, k = threadIdx.x;
  __shared__ float s_red[256];
  __shared__ double s_redd[256];
  const float T = 0.07f;
  float s = sumWA[(size_t)b*NB+k]/sumW[(size_t)b*NB+k];
  if (k==b) s *= -99.0f;
  const float lk = s/T;
  const float l0 = sim1[b]/T, ll = sim2[b]/T;
  s_red[k]=lk; __syncthreads();
  for (int st=128;st>0;st>>=1){ if(k<st) s_red[k]=fmaxf(s_red[k],s_red[k+st]); __syncthreads(); }
  const float m = fmaxf(s_red[0], fmaxf(l0,ll));
  __syncthreads();
  double e = (double)expf(lk-m);
  if (k==0) e += (double)expf(l0-m)+(double)expf(ll-m);
  s_redd[k]=e; __syncthreads();
  for (int st=128;st>0;st>>=1){ if(k<st) s_redd[k]+=s_redd[k+st]; __syncthreads(); }
  if (k==0) lossb[b] = -(float)((double)(l0-m) - log(s_redd[0]));
}

__global__ __launch_bounds__(256) void finalize_sum(const float* __restrict__ lossb, float* __restrict__ out_loss)
{
  const int tid = threadIdx.x;
  __shared__ double sr[256];
  sr[tid]=(double)lossb[tid]; __syncthreads();
  for (int st=128;st>0;st>>=1){ if(tid<st) sr[tid]+=sr[tid+st]; __syncthreads(); }
  if (tid==0) out_loss[0]=(float)(sr[0]/256.0);
}

// ================= FALLBACK PATH (R3, ~41MB ws) =================

__global__ __launch_bounds__(256) void prep_fb(
    const float* __restrict__ img, const float* __restrict__ aud,
    float* __restrict__ pl, float* __restrict__ cs, float* __restrict__ d0,
    float* __restrict__ sim1, float* __restrict__ sim2,
    float* __restrict__ out_pl)
{
  const int b = blockIdx.x, tid = threadIdx.x;
  const float* imgb = img + (size_t)b*NC*NP;
  __shared__ float s_aud[NC];
  __shared__ float s_wl[NP];
  __shared__ float s_nv[NC];
  __shared__ double s_redd[256];
  for (int c=tid;c<NC;c+=256) s_aud[c]=aud[b*NC+c];
  __syncthreads();
  float plv=0.f, pmw=0.f, negw=0.f;
  if (tid<NP){
    double a=0.0, s=0.0;
    for (int c=0;c<NC;++c){ float x=imgb[(size_t)c*NP+tid]; a += (double)x*(double)s_aud[c]; s += (double)x; }
    plv=(float)a;
    float csv=(float)s;
    pl[b*NP+tid]=plv; cs[b*NP+tid]=csv; out_pl[b*NP+tid]=plv;
    pmw  = sigf((plv-0.65f)/0.03f);
    negw = 1.0f - sigf((plv-0.40f)/0.03f);
    s_wl[tid]=plv*negw;
  }
  double r[4];
  r[0]=(tid<NP)?(double)pmw*(double)plv:0.0;
  r[1]=(tid<NP)?(double)pmw:0.0;
  r[2]=(tid<NP)?(double)negw*(double)plv:0.0;
  r[3]=(tid<NP)?(double)negw:0.0;
  double res[4];
  for (int i=0;i<4;++i){
    __syncthreads();
    s_redd[tid]=r[i];
    __syncthreads();
    for (int s=128;s>0;s>>=1){ if (tid<s) s_redd[tid]+=s_redd[tid+s]; __syncthreads(); }
    res[i]=s_redd[0];
  }
  if (tid==0){
    sim1[b]=(float)(res[0]/res[1]);
    sim2[b]=(float)(res[2]/res[3]);
  }
  __syncthreads();
  for (int c=tid;c<NC;c+=256){
    const float* row = imgb + (size_t)c*NP;
    double a=0.0;
    for (int p=0;p<NP;++p) a += (double)row[p]*(double)s_wl[p];
    s_nv[c]=(float)(a/(double)NP);
  }
  __syncthreads();
  if (tid<NP){
    double a=0.0;
    const double e=(double)1e-6f;
    for (int c=0;c<NC;++c){
      double t=(double)imgb[(size_t)c*NP+tid]*(double)plv - (double)s_nv[c] + e;
      a += t*t;
    }
    d0[b*NP+tid]=(float)sqrt(a);
  }
}

#define GKS 64
#define GSTR 72
#define SKS 128
#define SSTR 136

__device__ __forceinline__ bf16x8 frag_ld(const short* sm, int stride, int tile, int kk, int lane){
  int r = tile*16 + (lane & 15);
  int o = lane >> 4;
  const short* p = sm + r*stride + kk*32 + o*8;
  return *(const bf16x8*)p;
}

__global__ __launch_bounds__(512) void gram_fb(const float* __restrict__ img, float* __restrict__ G)
{
  const int b = blockIdx.x;
  const int tid = threadIdx.x, lane = tid & 63, w = tid >> 6;
  const int wr = w >> 1, wc = w & 1;
  const int rbase = (wr==0)?0:(3*wr+1), nr = (wr==0)?4:3;
  const int cbase = 7*wc, ncl = 7-wc;
  const float* imgb = img + (size_t)b*NC*NP;
  float* Gb = G + (size_t)b*NP*NP;
  __shared__ short smh[PROWS*GSTR];
  __shared__ short sml[PROWS*GSTR];

  f32x4 acc[4][7];
  #pragma unroll
  for (int i=0;i<4;++i)
    #pragma unroll
    for (int j=0;j<7;++j) acc[i][j] = (f32x4){0.f,0.f,0.f,0.f};

  for (int sl=0; sl<NC/GKS; ++sl){
    __syncthreads();
    #pragma unroll
    for (int it=0; it<4; ++it){
      int j = it*512 + tid;
      int p = j & 255, c8 = j >> 8;
      if (p < PROWS){
        float x[8];
        #pragma unroll
        for (int cc=0;cc<8;++cc){
          int c = sl*GKS + c8*8 + cc;
          x[cc] = (p<NP) ? imgb[(size_t)c*NP + p] : 0.f;
        }
        unsigned hw[4], lw[4];
        #pragma unroll
        for (int k2=0;k2<4;++k2){
          unsigned short h0=f2bf(x[2*k2]), h1=f2bf(x[2*k2+1]);
          float l0 = x[2*k2]-bf2f(h0), l1 = x[2*k2+1]-bf2f(h1);
          hw[k2] = (unsigned)h0 | ((unsigned)h1<<16);
          lw[k2] = (unsigned)f2bf(l0) | ((unsigned)f2bf(l1)<<16);
        }
        *(uint4*)&smh[p*GSTR + c8*8] = *(uint4*)hw;
        *(uint4*)&sml[p*GSTR + c8*8] = *(uint4*)lw;
      }
    }
    __syncthreads();
    #pragma unroll
    for (int kk=0; kk<GKS/32; ++kk){
      bf16x8 Ah[4], Al[4];
      #pragma unroll
      for (int i=0;i<4;++i){
        if (i<nr){ Ah[i]=frag_ld(smh,GSTR,rbase+i,kk,lane); Al[i]=frag_ld(sml,GSTR,rbase+i,kk,lane); }
      }
      #pragma unroll
      for (int j=0;j<7;++j){
        if (j<ncl){
          bf16x8 Bh = frag_ld(smh,GSTR,cbase+j,kk,lane);
          bf16x8 Bl = frag_ld(sml,GSTR,cbase+j,kk,lane);
          #pragma unroll
          for (int i=0;i<4;++i){
            if (i<nr){
              acc[i][j] = __builtin_amdgcn_mfma_f32_16x16x32_bf16(Ah[i], Bh, acc[i][j], 0,0,0);
              acc[i][j] = __builtin_amdgcn_mfma_f32_16x16x32_bf16(Ah[i], Bl, acc[i][j], 0,0,0);
              acc[i][j] = __builtin_amdgcn_mfma_f32_16x16x32_bf16(Al[i], Bh, acc[i][j], 0,0,0);
            }
          }
        }
      }
    }
  }

  const int r0 = (lane>>4)*4, colL = lane & 15;
  #pragma unroll
  for (int i=0;i<4;++i){
    #pragma unroll
    for (int j=0;j<7;++j){
      if (i<nr && j<ncl){
        int row = (rbase+i)*16 + r0;
        int col = (cbase+j)*16 + colL;
        if (col < NP){
          #pragma unroll
          for (int jj=0;jj<4;++jj){
            if (row+jj < NP) Gb[(size_t)(row+jj)*NP + col] = acc[i][j][jj];
          }
        }
      }
    }
  }
}

__global__ __launch_bounds__(512) void simgemm_fb(
    const float* __restrict__ img, const unsigned short* __restrict__ aud_bf,
    float* __restrict__ sumWA, float* __restrict__ sumW)
{
  const int b = blockIdx.x;
  const int tid = threadIdx.x, lane = tid & 63, w = tid >> 6;
  const int wr = w >> 2, wc = w & 3;
  const int pbase = (wr==0)?0:7, npt = 7-wr;
  const float* imgb = img + (size_t)b*NC*NP;
  __shared__ short smh[PROWS*SSTR];
  __shared__ float sred[2][2][4][4][16];

  f32x4 acc[7][4];
  #pragma unroll
  for (int i=0;i<7;++i)
    #pragma unroll
    for (int n=0;n<4;++n) acc[i][n] = (f32x4){0.f,0.f,0.f,0.f};

  for (int sl=0; sl<NC/SKS; ++sl){
    __syncthreads();
    #pragma unroll
    for (int it=0; it<8; ++it){
      int j = it*512 + tid;
      int p = j & 255, c8 = j >> 8;
      if (p < PROWS){
        float x[8];
        #pragma unroll
        for (int cc=0;cc<8;++cc){
          int c = sl*SKS + c8*8 + cc;
          x[cc] = (p<NP) ? imgb[(size_t)c*NP + p] : 0.f;
        }
        unsigned hw[4];
        #pragma unroll
        for (int k2=0;k2<4;++k2)
          hw[k2] = (unsigned)f2bf(x[2*k2]) | ((unsigned)f2bf(x[2*k2+1])<<16);
        *(uint4*)&smh[p*SSTR + c8*8] = *(uint4*)hw;
      }
    }
    __syncthreads();
    #pragma unroll
    for (int kk=0; kk<SKS/32; ++kk){
      bf16x8 Ah[7];
      #pragma unroll
      for (int i=0;i<7;++i)
        if (i<npt) Ah[i]=frag_ld(smh,SSTR,pbase+i,kk,lane);
      #pragma unroll
      for (int n=0;n<4;++n){
        int ntile = wc*4 + n;
        int k = ntile*16 + (lane&15);
        int c = sl*SKS + kk*32 + (lane>>4)*8;
        bf16x8 Bn = *(const bf16x8*)(aud_bf + (size_t)k*NC + c);
        #pragma unroll
        for (int i=0;i<7;++i)
          if (i<npt)
            acc[i][n] = __builtin_amdgcn_mfma_f32_16x16x32_bf16(Ah[i], Bn, acc[i][n], 0,0,0);
      }
    }
  }

  float swa[4]={0,0,0,0}, sw[4]={0,0,0,0};
  #pragma unroll
  for (int n=0;n<4;++n){
    #pragma unroll
    for (int i=0;i<7;++i){
      if (i<npt){
        int rowbase = (pbase+i)*16 + (lane>>4)*4;
        #pragma unroll
        for (int jj=0;jj<4;++jj){
          if (rowbase+jj < NP){
            float v = acc[i][n][jj];
            float wgt = sigf((v-0.65f)/0.03f);
            swa[n] += wgt*v; sw[n] += wgt;
          }
        }
      }
    }
  }
  #pragma unroll
  for (int n=0;n<4;++n){
    swa[n] += __shfl_xor(swa[n],16); swa[n] += __shfl_xor(swa[n],32);
    sw[n]  += __shfl_xor(sw[n],16);  sw[n]  += __shfl_xor(sw[n],32);
  }
  if (lane < 16){
    #pragma unroll
    for (int n=0;n<4;++n){
      sred[0][wr][wc][n][lane] = swa[n];
      sred[1][wr][wc][n][lane] = sw[n];
    }
  }
  __syncthreads();
  if (tid < 256){
    int wc2 = tid>>6, n2 = (tid>>4)&3, col = tid&15;
    float a = sred[0][0][wc2][n2][col] + sred[0][1][wc2][n2][col];
    float s = sred[1][0][wc2][n2][col] + sred[1][1][wc2][n2][col];
    sumWA[(size_t)b*NB + tid] = a;
    sumW [(size_t)b*NB + tid] = s;
  }
}

__global__ __launch_bounds__(64) void loop_fb(
    const float* __restrict__ img, const float* __restrict__ pl,
    const float* __restrict__ cs, const float* __restrict__ d0,
    const float* __restrict__ G, float* __restrict__ obj)
{
  const int b = blockIdx.x, lane = threadIdx.x;
  const float* imgb = img + (size_t)b*NC*NP;
  const float* Gb = G + (size_t)b*NP*NP;

  float plv[4], csL[4], d0v[4], gdd[4], posv[4];
  bool alr[4];
  #pragma unroll
  for (int s=0;s<4;++s){
    int p = lane + 64*s;
    bool valid = p < NP;
    plv[s] = valid ? pl[b*NP+p] : 0.f;
    csL[s] = valid ? plv[s]*cs[b*NP+p] : 0.f;
    d0v[s] = valid ? d0[b*NP+p] : 0.f;
    gdd[s] = valid ? Gb[(size_t)p*NP+p] : 0.f;
    posv[s] = valid ? plv[s] : -INFINITY;
    alr[s] = false;
  }
  bool endp = false;

  for (int t=0;t<NIT;++t){
    float v = posv[0]; int ix = lane;
    #pragma unroll
    for (int s=1;s<4;++s){
      if (posv[s] > v){ v = posv[s]; ix = lane + 64*s; }
    }
    #pragma unroll
    for (int m=1;m<64;m<<=1){
      float vv = __shfl_xor(v, m);
      int   ii = __shfl_xor(ix, m);
      if (vv>v || (vv==v && ii<ix)){ v=vv; ix=ii; }
    }
    const int q = ix;
    const int slot = q >> 6, ln = q & 63;
    float pq=0.f, gq=0.f, cq=0.f;
    #pragma unroll
    for (int s=0;s<4;++s){
      if (s==slot){ pq=plv[s]; gq=gdd[s]; cq=csL[s]; }
    }
    const float plq  = __shfl(pq, ln);
    const float gqq  = __shfl(gq, ln);
    const float csLq = __shfl(cq, ln);

    {
      float* op = obj + ((size_t)t*NB + b)*NC;
      #pragma unroll
      for (int j2=0;j2<8;++j2){
        int c = lane + 64*j2;
        op[c] = endp ? 0.0f : imgb[(size_t)c*NP + q]*plq;
      }
    }

    int cnt = 0;
    #pragma unroll
    for (int s=0;s<4;++s){
      int p = lane + 64*s;
      if (p<NP && !alr[s]){
        float Gpq = Gb[(size_t)q*NP + p];
        double plp=(double)plv[s], dq=(double)plq;
        const double e=(double)1e-6f;
        double d2 = plp*plp*(double)gdd[s]
                  - 2.0*plp*dq*(double)Gpq
                  + dq*dq*(double)gqq
                  + 2.0*e*((double)csL[s]-(double)csLq)
                  + (double)NC*e*e;
        if (d2<0.0) d2=0.0;
        if (sqrt(d2) < (double)d0v[s]){ alr[s]=true; posv[s]=posv[s]*0.0f; cnt++; }
      }
    }
    float mx = fmaxf(fmaxf(posv[0],posv[1]),fmaxf(posv[2],posv[3]));
    #pragma unroll
    for (int m=1;m<64;m<<=1){
      cnt += __shfl_xor(cnt, m);
      mx = fmaxf(mx, __shfl_xor(mx, m));
    }
    if (cnt==0 || mx<0.1f) endp=true;
  }
}

__global__ __launch_bounds__(256) void finalize_fb(
    const float* __restrict__ sim1, const float* __restrict__ sim2,
    const float* __restrict__ sumWA, const float* __restrict__ sumW,
    float* __restrict__ out_loss)
{
  const int b = threadIdx.x;
  const float T = 0.07f;
  float l0 = sim1[b]/T;
  float ll = sim2[b]/T;
  float m = fmaxf(l0,ll);
  for (int k=0;k<NB;++k){
    float s = sumWA[(size_t)b*NB+k]/sumW[(size_t)b*NB+k];
    if (k==b) s *= -99.0f;
    m = fmaxf(m, s/T);
  }
  double se = exp((double)(l0-m)) + exp((double)(ll-m));
  for (int k=0;k<NB;++k){
    float s = sumWA[(size_t)b*NB+k]/sumW[(size_t)b*NB+k];
    if (k==b) s *= -99.0f;
    se += exp((double)(s/T-m));
  }
  float lsm0 = (float)((double)(l0-m) - log(se));
  __shared__ double s_redd[256];
  s_redd[b] = -(double)lsm0;
  __syncthreads();
  for (int s=128;s>0;s>>=1){ if (b<s) s_redd[b]+=s_redd[b+s]; __syncthreads(); }
  if (b==0) out_loss[0]=(float)(s_redd[0]/(double)NB);
}

extern "C" void kernel_launch(void* const* d_in, const int* in_sizes, int n_in,
                              void* d_out, int out_size, void* d_ws, size_t ws_size,
                              hipStream_t stream)
{
  const float* img = (const float*)d_in[0];
  const float* aud = (const float*)d_in[1];
  float* out = (float*)d_out;
  float* ws  = (float*)d_ws;

  // ws layout (floats)
  float* pl    = ws;                        // 50176
  float* cs    = pl    + NB*NP;             // 50176
  float* d0    = cs    + NB*NP;             // 50176 (fallback only)
  float* sim1  = d0    + NB*NP;             // 256
  float* sim2  = sim1  + NB;                // 256
  float* sumWA = sim2  + NB;                // 65536
  float* sumW  = sumWA + NB*NB;             // 65536
  unsigned short* aud_bf = (unsigned short*)(sumW + NB*NB);   // 131072 ushorts
  float* G     = (float*)(aud_bf + NB*NC);  // 9,834,496 floats
  unsigned short* hiT = (unsigned short*)(G + (size_t)NB*NP*NP);
  unsigned short* loT = hiT + (size_t)NB*PROWS*NC;
  int* qseq    = (int*)(loT + (size_t)NB*PROWS*NC);           // 8192 ints
  int* zf      = qseq + NB*NIT;                               // 8192 ints
  float* lossb = (float*)(zf + NB*NIT);                       // 256 floats

  // pl/cs partials overlay the G region (consumed by prep3 BEFORE gram2 writes G)
  double* ppl = (double*)G;                 // NB*4*196 doubles (1.6 MB)
  double* pcs = ppl + (size_t)NB*4*NP;      // NB*4*196 doubles

  const size_t need_fast = (size_t)((char*)(lossb + NB) - (char*)ws);

  float* out_loss = out;
  float* out_pl   = out + 1;
  float* out_obj  = out + 1 + NB*NP;

  hipLaunchKernelGGL(aud2bf_kernel, dim3(NB*NC/256), dim3(256), 0, stream, aud, aud_bf);

  if (ws_size >= need_fast){
    hipLaunchKernelGGL(convert3_kernel, dim3(NB*4),   dim3(512), 0, stream, img, aud, hiT, loT, ppl, pcs);
    hipLaunchKernelGGL(prep3_kernel,    dim3(NB),     dim3(256), 0, stream, ppl, pcs, pl, cs, sim1, sim2, out_pl);
    hipLaunchKernelGGL(gram2_kernel,    dim3(NB*2),   dim3(512), 0, stream, hiT, loT, G);
    hipLaunchKernelGGL(loop3_kernel,    dim3(NB),     dim3(256), 0, stream, pl, cs, G, qseq, zf);
    hipLaunchKernelGGL(simgemm2_kernel, dim3(NB*2),   dim3(512), 0, stream, hiT, aud_bf, sumWA, sumW);
    hipLaunchKernelGGL(objw_kernel,     dim3(NB*NIT), dim3(64),  0, stream, hiT, loT, pl, qseq, zf, out_obj);
    hipLaunchKernelGGL(finalize_b,      dim3(NB),     dim3(256), 0, stream, sim1, sim2, sumWA, sumW, lossb);
    hipLaunchKernelGGL(finalize_sum,    dim3(1),      dim3(256), 0, stream, lossb, out_loss);
  } else {
    hipLaunchKernelGGL(prep_fb,    dim3(NB), dim3(256), 0, stream, img, aud, pl, cs, d0, sim1, sim2, out_pl);
    hipLaunchKernelGGL(gram_fb,    dim3(NB), dim3(512), 0, stream, img, G);
    hipLaunchKernelGGL(simgemm_fb, dim3(NB), dim3(512), 0, stream, img, aud_bf, sumWA, sumW);
    hipLaunchKernelGGL(loop_fb,    dim3(NB), dim3(64),  0, stream, img, pl, cs, d0, G, out_obj);
    hipLaunchKernelGGL(finalize_fb,dim3(1),  dim3(256), 0, stream, sim1, sim2, sumWA, sumW, out_loss);
  }
}